// Round 10
// baseline (18929.543 us; speedup 1.0000x reference)
//
#include <hip/hip_runtime.h>
#include <math.h>

// XFADS: N=32, T=1024, D_OBS=128, D_Z=64, D_U=8, H_ENC=256, H_BW=128, H_DYN=256, D_A=128
#define T_LEN 1024
#define NB 32

typedef _Float16 f16x8 __attribute__((ext_vector_type(8)));
typedef _Float16 f16x4 __attribute__((ext_vector_type(4)));
typedef float f32x4 __attribute__((ext_vector_type(4)));

__device__ __forceinline__ float softplus_f(float x) {
    return fmaxf(x, 0.f) + log1pf(expf(-fabsf(x)));
}

__device__ __forceinline__ float fast_tanh(float x) {
    float e = __builtin_amdgcn_exp2f(x * 2.88539008177792681472f);
    float r = __builtin_amdgcn_rcpf(1.f + e);
    return 1.f - 2.f * r;
}

// raw barrier: drain LDS ops only; global prefetches stay in flight (T4 pattern)
__device__ __forceinline__ void bar_sync() {
    asm volatile("s_waitcnt lgkmcnt(0)" ::: "memory");
    __builtin_amdgcn_s_barrier();
    asm volatile("" ::: "memory");
}

// swizzled f16-row addressing: row b (stride R f16), element idx.
#define SWZ(b, R, idx) ((b)*(R) + ((((idx) >> 3) ^ ((b) & 7)) << 3) + ((idx) & 7))

// -------------------------------------------------------------------------
// K1: encoder  h = tanh(y@W1+b1); a = h@W2+b2;
//     apre16[t][n][:] = f16(a@bw_wa + bw_b)
//     preU16[t][n][:] = f16(u@dyn_w1[64:72] + dyn_b1)
// -------------------------------------------------------------------------
__global__ __launch_bounds__(256) void k_encoder(
    const float* __restrict__ y, const float* __restrict__ u,
    const float* __restrict__ w1, const float* __restrict__ b1,
    const float* __restrict__ w2, const float* __restrict__ b2,
    const float* __restrict__ wa, const float* __restrict__ bb,
    const float* __restrict__ dynw1, const float* __restrict__ dynb1,
    _Float16* __restrict__ apre16, _Float16* __restrict__ preU16)
{
    __shared__ float ly[8][128];
    __shared__ float lh[8][256];
    __shared__ float la[8][128];
    __shared__ float lu[8][8];
    const int tid = threadIdx.x;
    const int row0 = blockIdx.x * 8;

    ((float4*)&ly[0][0])[tid] = ((const float4*)(y + (size_t)row0 * 128))[tid];
    if (tid < 16)
        ((float4*)&lu[0][0])[tid] = ((const float4*)(u + (size_t)row0 * 8))[tid];
    __syncthreads();

    {
        float acc[8] = {0,0,0,0,0,0,0,0};
        for (int i = 0; i < 128; i += 4) {
            float w0 = w1[(i+0)*256 + tid];
            float w1v = w1[(i+1)*256 + tid];
            float w2v = w1[(i+2)*256 + tid];
            float w3 = w1[(i+3)*256 + tid];
            #pragma unroll
            for (int r = 0; r < 8; ++r) {
                float4 yv = *(const float4*)&ly[r][i];
                acc[r] += yv.x*w0 + yv.y*w1v + yv.z*w2v + yv.w*w3;
            }
        }
        float bias = b1[tid];
        #pragma unroll
        for (int r = 0; r < 8; ++r) lh[r][tid] = fast_tanh(acc[r] + bias);
    }
    __syncthreads();

    {
        const int d = tid & 127, rh = tid >> 7;
        float acc[4] = {0,0,0,0};
        for (int i = 0; i < 256; i += 4) {
            float w0 = w2[(i+0)*128 + d];
            float w1v = w2[(i+1)*128 + d];
            float w2v = w2[(i+2)*128 + d];
            float w3 = w2[(i+3)*128 + d];
            #pragma unroll
            for (int q = 0; q < 4; ++q) {
                float4 hv = *(const float4*)&lh[rh*4+q][i];
                acc[q] += hv.x*w0 + hv.y*w1v + hv.z*w2v + hv.w*w3;
            }
        }
        float bias = b2[d];
        #pragma unroll
        for (int q = 0; q < 4; ++q) la[rh*4+q][d] = acc[q] + bias;
    }
    __syncthreads();

    {
        const int j = tid & 127, rh = tid >> 7;
        float acc[4] = {0,0,0,0};
        for (int i = 0; i < 128; i += 4) {
            float w0 = wa[(i+0)*128 + j];
            float w1v = wa[(i+1)*128 + j];
            float w2v = wa[(i+2)*128 + j];
            float w3 = wa[(i+3)*128 + j];
            #pragma unroll
            for (int q = 0; q < 4; ++q) {
                float4 av = *(const float4*)&la[rh*4+q][i];
                acc[q] += av.x*w0 + av.y*w1v + av.z*w2v + av.w*w3;
            }
        }
        float bias = bb[j];
        #pragma unroll
        for (int q = 0; q < 4; ++q) {
            int rn = row0 + rh*4 + q;
            int n = rn >> 10, t = rn & 1023;
            apre16[((size_t)t*NB + n)*128 + j] = (_Float16)(acc[q] + bias);
        }
    }

    {
        float wu[8];
        #pragma unroll
        for (int c = 0; c < 8; ++c) wu[c] = dynw1[(64 + c)*256 + tid];
        float bias = dynb1[tid];
        #pragma unroll
        for (int r = 0; r < 8; ++r) {
            float acc = bias;
            #pragma unroll
            for (int c = 0; c < 8; ++c) acc += lu[r][c] * wu[c];
            int rn = row0 + r;
            int n = rn >> 10, t = rn & 1023;
            preU16[((size_t)t*NB + n)*256 + tid] = (_Float16)acc;
        }
    }
}

// -------------------------------------------------------------------------
// K2: backward scan, transposed MFMA, 8 blocks x 4 REAL batches (12 pad).
// H'^T = tanh(apre^T + Wh^T @ H^T). Pad cols run on zeros; loads/stores
// masked by c<4. 1 barrier/step; prefetch ring distance 2 (f16 inputs).
// -------------------------------------------------------------------------
__global__ __launch_bounds__(256, 1) void k_bwscan(
    const _Float16* __restrict__ apre16, const float* __restrict__ wh,
    _Float16* __restrict__ hcell16)
{
    const int nb = blockIdx.x * 4;
    const int tid = threadIdx.x;
    const int w = tid >> 6, l = tid & 63;
    const int g = l >> 4, c = l & 15;
    __shared__ __align__(16) _Float16 Hl[2][16 * 128];

    f16x8 Af[2][4];
    #pragma unroll
    for (int jj = 0; jj < 2; ++jj)
        #pragma unroll
        for (int kt = 0; kt < 4; ++kt) {
            f16x8 v;
            #pragma unroll
            for (int i = 0; i < 8; ++i)
                v[i] = (_Float16)wh[(size_t)(kt*32 + g*8 + i)*128 + (2*w + jj)*16 + c];
            Af[jj][kt] = v;
        }

    for (int e = tid; e < 16 * 128; e += 256) Hl[0][e] = (_Float16)0.f;
    __syncthreads();

    const bool act = (c < 4);
    const int myb = nb + c;

    f16x4 apr[2][2];
#define LOADB(s, tt) do { \
        if (act && (tt) >= 0) { \
            size_t ab = ((size_t)(tt)*NB + myb)*128; \
            apr[s][0] = *(const f16x4*)&apre16[ab + (2*w + 0)*16 + g*4]; \
            apr[s][1] = *(const f16x4*)&apre16[ab + (2*w + 1)*16 + g*4]; \
        } else { \
            apr[s][0] = (_Float16)0; apr[s][1] = (_Float16)0; \
        } } while (0)

    LOADB(1, 1023);
    LOADB(0, 1022);

    int cur = 0;
    for (int t = 1023; t >= 0; --t) {
        const int s = t & 1;
        float apf[2][4];
        #pragma unroll
        for (int jj = 0; jj < 2; ++jj)
            #pragma unroll
            for (int r = 0; r < 4; ++r) apf[jj][r] = (float)apr[s][jj][r];
        LOADB(s, t - 2);

        f16x8 b0 = *(const f16x8*)&Hl[cur][SWZ(c, 128, 0*32 + g*8)];
        f16x8 b1 = *(const f16x8*)&Hl[cur][SWZ(c, 128, 1*32 + g*8)];
        f16x8 b2 = *(const f16x8*)&Hl[cur][SWZ(c, 128, 2*32 + g*8)];
        f16x8 b3 = *(const f16x8*)&Hl[cur][SWZ(c, 128, 3*32 + g*8)];

        #pragma unroll
        for (int jj = 0; jj < 2; ++jj) {
            f32x4 aA = {0.f,0.f,0.f,0.f}, aB = {0.f,0.f,0.f,0.f};
            aA = __builtin_amdgcn_mfma_f32_16x16x32_f16(Af[jj][0], b0, aA, 0, 0, 0);
            aB = __builtin_amdgcn_mfma_f32_16x16x32_f16(Af[jj][1], b1, aB, 0, 0, 0);
            aA = __builtin_amdgcn_mfma_f32_16x16x32_f16(Af[jj][2], b2, aA, 0, 0, 0);
            aB = __builtin_amdgcn_mfma_f32_16x16x32_f16(Af[jj][3], b3, aB, 0, 0, 0);
            f32x4 acc = aA + aB;

            const int j0 = (2*w + jj)*16 + g*4;
            f16x4 hh;
            #pragma unroll
            for (int r = 0; r < 4; ++r)
                hh[r] = (_Float16)fast_tanh(acc[r] + apf[jj][r]);
            *(f16x4*)&Hl[cur ^ 1][SWZ(c, 128, j0)] = hh;
            if (act)
                *(f16x4*)&hcell16[((size_t)t*NB + myb)*128 + j0] = hh;
        }
        bar_sync();
        cur ^= 1;
    }
#undef LOADB
}

// -------------------------------------------------------------------------
// K3: b = hcell @ wo + bo; alpha16 = f16([b[:64], -softplus(b[64:])])
// -------------------------------------------------------------------------
__global__ __launch_bounds__(256) void k_alpha(
    const _Float16* __restrict__ hcell16, const float* __restrict__ wo,
    const float* __restrict__ bo, _Float16* __restrict__ alpha16)
{
    __shared__ float lhc[8][128];
    const int tid = threadIdx.x;
    const size_t base = (size_t)blockIdx.x * 8 * 128;
    {
        f16x4 hv = *(const f16x4*)&hcell16[base + tid*4];
        float4 f;
        #pragma unroll
        for (int r = 0; r < 4; ++r) ((float*)&f)[r] = (float)hv[r];
        ((float4*)&lhc[0][0])[tid] = f;
    }
    __syncthreads();

    const int j = tid & 127, rh = tid >> 7;
    float acc[4] = {0,0,0,0};
    for (int i = 0; i < 128; i += 4) {
        float w0 = wo[(i+0)*128 + j];
        float w1v = wo[(i+1)*128 + j];
        float w2v = wo[(i+2)*128 + j];
        float w3 = wo[(i+3)*128 + j];
        #pragma unroll
        for (int q = 0; q < 4; ++q) {
            float4 hv = *(const float4*)&lhc[rh*4+q][i];
            acc[q] += hv.x*w0 + hv.y*w1v + hv.z*w2v + hv.w*w3;
        }
    }
    float bias = bo[j];
    #pragma unroll
    for (int q = 0; q < 4; ++q) {
        float b = acc[q] + bias;
        float val = (j < 64) ? b : -softplus_f(b);
        alpha16[base + (size_t)(rh*4+q)*128 + j] = (_Float16)val;
    }
}

// -------------------------------------------------------------------------
// K4: forward scan, transposed MFMA, 8 blocks x 4 REAL batches (12 pad).
// G1: HID^T = tanh(preU^T + W1m^T @ M^T); G2: PRED^T = W2^T @ HID^T.
// 2 barriers/step; f16 inputs; prefetch ring distance 2.
// -------------------------------------------------------------------------
__global__ __launch_bounds__(256, 1) void k_fwscan(
    const _Float16* __restrict__ alpha16, const _Float16* __restrict__ preU16,
    const float* __restrict__ dynw1, const float* __restrict__ dynw2,
    const float* __restrict__ dynb2, const float* __restrict__ qraw,
    const float* __restrict__ m0, const float* __restrict__ v0,
    float* __restrict__ out)
{
    const int nb = blockIdx.x * 4;
    const int tid = threadIdx.x;
    const int w = tid >> 6, l = tid & 63;
    const int g = l >> 4, c = l & 15;
    __shared__ __align__(16) _Float16 Mld[16 * 64];
    __shared__ __align__(16) _Float16 Hidl[16 * 256];

    f16x8 A1[4][2];
    #pragma unroll
    for (int hti = 0; hti < 4; ++hti)
        #pragma unroll
        for (int kt = 0; kt < 2; ++kt) {
            f16x8 v;
            #pragma unroll
            for (int i = 0; i < 8; ++i)
                v[i] = (_Float16)dynw1[(size_t)(kt*32 + g*8 + i)*256 + (w*4 + hti)*16 + c];
            A1[hti][kt] = v;
        }
    f16x8 A2[8];
    #pragma unroll
    for (int kt = 0; kt < 8; ++kt) {
        f16x8 v;
        #pragma unroll
        for (int i = 0; i < 8; ++i)
            v[i] = (_Float16)dynw2[(size_t)(kt*32 + g*8 + i)*64 + w*16 + c];
        A2[kt] = v;
    }

    const int d0 = w*16 + g*4;
    float Qv[4], b2v4[4], vreg[4];
    #pragma unroll
    for (int r = 0; r < 4; ++r) {
        Qv[r]   = softplus_f(qraw[d0 + r]);
        b2v4[r] = dynb2[d0 + r];
        vreg[r] = v0[d0 + r];
    }

    for (int e = tid; e < 1024; e += 256) {
        int b = e >> 6, dd = e & 63;
        Mld[SWZ(b, 64, dd)] = (_Float16)m0[dd];
    }
    __syncthreads();

    const bool act = (c < 4);
    const int myb = nb + c;

    f16x4 hpr[2][4], a1r[2], a2r[2];
#define LOADSTEP(s, tt) do { \
        if (act && (tt) < T_LEN) { \
            size_t pb = ((size_t)(tt)*NB + myb)*256; \
            hpr[s][0] = *(const f16x4*)&preU16[pb + (w*4 + 0)*16 + g*4]; \
            hpr[s][1] = *(const f16x4*)&preU16[pb + (w*4 + 1)*16 + g*4]; \
            hpr[s][2] = *(const f16x4*)&preU16[pb + (w*4 + 2)*16 + g*4]; \
            hpr[s][3] = *(const f16x4*)&preU16[pb + (w*4 + 3)*16 + g*4]; \
            size_t ab = ((size_t)(tt)*NB + myb)*128; \
            a1r[s] = *(const f16x4*)&alpha16[ab + d0]; \
            a2r[s] = *(const f16x4*)&alpha16[ab + 64 + d0]; \
        } else { \
            hpr[s][0] = (_Float16)0; hpr[s][1] = (_Float16)0; \
            hpr[s][2] = (_Float16)0; hpr[s][3] = (_Float16)0; \
            a1r[s] = (_Float16)0; a2r[s] = (_Float16)0; \
        } } while (0)

    LOADSTEP(0, 0);
    LOADSTEP(1, 1);

    for (int t = 0; t < T_LEN; ++t) {
        const int s = t & 1;
        float hpf[4][4], al1f[4], al2f[4];
        #pragma unroll
        for (int hti = 0; hti < 4; ++hti)
            #pragma unroll
            for (int r = 0; r < 4; ++r) hpf[hti][r] = (float)hpr[s][hti][r];
        #pragma unroll
        for (int r = 0; r < 4; ++r) {
            al1f[r] = (float)a1r[s][r];
            al2f[r] = (float)a2r[s][r];
        }
        LOADSTEP(s, t + 2);

        // G1
        f16x8 bm0 = *(const f16x8*)&Mld[SWZ(c, 64, 0*32 + g*8)];
        f16x8 bm1 = *(const f16x8*)&Mld[SWZ(c, 64, 1*32 + g*8)];
        #pragma unroll
        for (int hti = 0; hti < 4; ++hti) {
            f32x4 aA = {0.f,0.f,0.f,0.f}, aB = {0.f,0.f,0.f,0.f};
            aA = __builtin_amdgcn_mfma_f32_16x16x32_f16(A1[hti][0], bm0, aA, 0, 0, 0);
            aB = __builtin_amdgcn_mfma_f32_16x16x32_f16(A1[hti][1], bm1, aB, 0, 0, 0);
            f32x4 acc = aA + aB;
            const int h0 = (w*4 + hti)*16 + g*4;
            f16x4 hh;
            #pragma unroll
            for (int r = 0; r < 4; ++r)
                hh[r] = (_Float16)fast_tanh(hpf[hti][r] + acc[r]);
            *(f16x4*)&Hidl[SWZ(c, 256, h0)] = hh;
        }
        bar_sync();   // HID ready; M reads done

        // G2
        f32x4 aA = {0.f,0.f,0.f,0.f}, aB = {0.f,0.f,0.f,0.f};
        #pragma unroll
        for (int kt = 0; kt < 8; kt += 2) {
            f16x8 h0v = *(const f16x8*)&Hidl[SWZ(c, 256, kt*32 + g*8)];
            f16x8 h1v = *(const f16x8*)&Hidl[SWZ(c, 256, (kt+1)*32 + g*8)];
            aA = __builtin_amdgcn_mfma_f32_16x16x32_f16(A2[kt],   h0v, aA, 0, 0, 0);
            aB = __builtin_amdgcn_mfma_f32_16x16x32_f16(A2[kt+1], h1v, aB, 0, 0, 0);
        }
        f32x4 acc2 = aA + aB;

        // epilogue
        float4 oms, ovs, omp, ovp;
        f16x4 mm;
        #pragma unroll
        for (int r = 0; r < 4; ++r) {
            float m_p = acc2[r] + b2v4[r];
            float v_p = vreg[r] + Qv[r];
            float rvp = __builtin_amdgcn_rcpf(v_p);
            float e1 = m_p * rvp + al1f[r];
            float e2 = al2f[r] - 0.5f * rvp;
            float v_s = -0.5f * __builtin_amdgcn_rcpf(e2);
            float m_s = v_s * e1;
            vreg[r] = v_s;
            ((float*)&oms)[r] = m_s; ((float*)&ovs)[r] = v_s;
            ((float*)&omp)[r] = m_p; ((float*)&ovp)[r] = v_p;
            mm[r] = (_Float16)m_s;
        }
        *(f16x4*)&Mld[SWZ(c, 64, d0)] = mm;
        if (act) {
            size_t ob = ((size_t)myb*T_LEN + t)*256;
            *(float4*)&out[ob + d0]        = oms;
            *(float4*)&out[ob + 64 + d0]   = ovs;
            *(float4*)&out[ob + 128 + d0]  = omp;
            *(float4*)&out[ob + 192 + d0]  = ovp;
        }
        bar_sync();   // M update visible before next G1 reads
    }
#undef LOADSTEP
}

// -------------------------------------------------------------------------
extern "C" void kernel_launch(void* const* d_in, const int* in_sizes, int n_in,
                              void* d_out, int out_size, void* d_ws, size_t ws_size,
                              hipStream_t stream) {
    const float* y      = (const float*)d_in[1];
    const float* u      = (const float*)d_in[2];
    const float* enc_w1 = (const float*)d_in[3];
    const float* enc_b1 = (const float*)d_in[4];
    const float* enc_w2 = (const float*)d_in[5];
    const float* enc_b2 = (const float*)d_in[6];
    const float* bw_wa  = (const float*)d_in[7];
    const float* bw_wh  = (const float*)d_in[8];
    const float* bw_b   = (const float*)d_in[9];
    const float* bw_wo  = (const float*)d_in[10];
    const float* bw_bo  = (const float*)d_in[11];
    const float* dyn_w1 = (const float*)d_in[12];
    const float* dyn_b1 = (const float*)d_in[13];
    const float* dyn_w2 = (const float*)d_in[14];
    const float* dyn_b2 = (const float*)d_in[15];
    const float* q_raw  = (const float*)d_in[16];
    const float* m0     = (const float*)d_in[17];
    const float* v0     = (const float*)d_in[18];
    float* out = (float*)d_out;

    // workspace (f16): apre/alpha alias 8MB, hcell 8MB, preU 16MB
    _Float16* ws16 = (_Float16*)d_ws;
    _Float16* apre16  = ws16;                    // [T*NB][128]
    _Float16* hcell16 = ws16 + 4194304;          // [T*NB][128]
    _Float16* alpha16 = ws16;                    // aliases apre
    _Float16* preU16  = ws16 + 2 * 4194304;      // [T*NB][256]

    k_encoder<<<4096, 256, 0, stream>>>(y, u, enc_w1, enc_b1, enc_w2, enc_b2,
                                        bw_wa, bw_b, dyn_w1, dyn_b1, apre16, preU16);
    k_bwscan<<<8, 256, 0, stream>>>(apre16, bw_wh, hcell16);
    k_alpha<<<4096, 256, 0, stream>>>(hcell16, bw_wo, bw_bo, alpha16);
    k_fwscan<<<8, 256, 0, stream>>>(alpha16, preU16, dyn_w1, dyn_w2, dyn_b2,
                                    q_raw, m0, v0, out);
}

// Round 11
// 2323.052 us; speedup vs baseline: 8.1486x; 8.1486x over previous
//
#include <hip/hip_runtime.h>
#include <math.h>

// XFADS: N=32, T=1024, D_OBS=128, D_Z=64, D_U=8, H_ENC=256, H_BW=128, H_DYN=256, D_A=128
#define T_LEN 1024
#define NB 32

typedef _Float16 f16x8 __attribute__((ext_vector_type(8)));
typedef _Float16 f16x4 __attribute__((ext_vector_type(4)));
typedef float f32x4 __attribute__((ext_vector_type(4)));

__device__ __forceinline__ float softplus_f(float x) {
    return fmaxf(x, 0.f) + log1pf(expf(-fabsf(x)));
}

__device__ __forceinline__ float fast_tanh(float x) {
    float e = __builtin_amdgcn_exp2f(x * 2.88539008177792681472f);
    float r = __builtin_amdgcn_rcpf(1.f + e);
    return 1.f - 2.f * r;
}

// raw barrier: drain LDS ops only; global prefetches stay in flight (T4 pattern)
__device__ __forceinline__ void bar_sync() {
    asm volatile("s_waitcnt lgkmcnt(0)" ::: "memory");
    __builtin_amdgcn_s_barrier();
    asm volatile("" ::: "memory");
}

// swizzled f16-row addressing: row b (stride R f16), element idx.
#define SWZ(b, R, idx) ((b)*(R) + ((((idx) >> 3) ^ ((b) & 7)) << 3) + ((idx) & 7))

// -------------------------------------------------------------------------
// K1: encoder  h = tanh(y@W1+b1); a = h@W2+b2;
//     apre16[t][n][:] = f16(a@bw_wa + bw_b)
//     preU16[t][n][:] = f16(u@dyn_w1[64:72] + dyn_b1)
// -------------------------------------------------------------------------
__global__ __launch_bounds__(256) void k_encoder(
    const float* __restrict__ y, const float* __restrict__ u,
    const float* __restrict__ w1, const float* __restrict__ b1,
    const float* __restrict__ w2, const float* __restrict__ b2,
    const float* __restrict__ wa, const float* __restrict__ bb,
    const float* __restrict__ dynw1, const float* __restrict__ dynb1,
    _Float16* __restrict__ apre16, _Float16* __restrict__ preU16)
{
    __shared__ float ly[8][128];
    __shared__ float lh[8][256];
    __shared__ float la[8][128];
    __shared__ float lu[8][8];
    const int tid = threadIdx.x;
    const int row0 = blockIdx.x * 8;

    ((float4*)&ly[0][0])[tid] = ((const float4*)(y + (size_t)row0 * 128))[tid];
    if (tid < 16)
        ((float4*)&lu[0][0])[tid] = ((const float4*)(u + (size_t)row0 * 8))[tid];
    __syncthreads();

    {
        float acc[8] = {0,0,0,0,0,0,0,0};
        for (int i = 0; i < 128; i += 4) {
            float w0 = w1[(i+0)*256 + tid];
            float w1v = w1[(i+1)*256 + tid];
            float w2v = w1[(i+2)*256 + tid];
            float w3 = w1[(i+3)*256 + tid];
            #pragma unroll
            for (int r = 0; r < 8; ++r) {
                float4 yv = *(const float4*)&ly[r][i];
                acc[r] += yv.x*w0 + yv.y*w1v + yv.z*w2v + yv.w*w3;
            }
        }
        float bias = b1[tid];
        #pragma unroll
        for (int r = 0; r < 8; ++r) lh[r][tid] = fast_tanh(acc[r] + bias);
    }
    __syncthreads();

    {
        const int d = tid & 127, rh = tid >> 7;
        float acc[4] = {0,0,0,0};
        for (int i = 0; i < 256; i += 4) {
            float w0 = w2[(i+0)*128 + d];
            float w1v = w2[(i+1)*128 + d];
            float w2v = w2[(i+2)*128 + d];
            float w3 = w2[(i+3)*128 + d];
            #pragma unroll
            for (int q = 0; q < 4; ++q) {
                float4 hv = *(const float4*)&lh[rh*4+q][i];
                acc[q] += hv.x*w0 + hv.y*w1v + hv.z*w2v + hv.w*w3;
            }
        }
        float bias = b2[d];
        #pragma unroll
        for (int q = 0; q < 4; ++q) la[rh*4+q][d] = acc[q] + bias;
    }
    __syncthreads();

    {
        const int j = tid & 127, rh = tid >> 7;
        float acc[4] = {0,0,0,0};
        for (int i = 0; i < 128; i += 4) {
            float w0 = wa[(i+0)*128 + j];
            float w1v = wa[(i+1)*128 + j];
            float w2v = wa[(i+2)*128 + j];
            float w3 = wa[(i+3)*128 + j];
            #pragma unroll
            for (int q = 0; q < 4; ++q) {
                float4 av = *(const float4*)&la[rh*4+q][i];
                acc[q] += av.x*w0 + av.y*w1v + av.z*w2v + av.w*w3;
            }
        }
        float bias = bb[j];
        #pragma unroll
        for (int q = 0; q < 4; ++q) {
            int rn = row0 + rh*4 + q;
            int n = rn >> 10, t = rn & 1023;
            apre16[((size_t)t*NB + n)*128 + j] = (_Float16)(acc[q] + bias);
        }
    }

    {
        float wu[8];
        #pragma unroll
        for (int c = 0; c < 8; ++c) wu[c] = dynw1[(64 + c)*256 + tid];
        float bias = dynb1[tid];
        #pragma unroll
        for (int r = 0; r < 8; ++r) {
            float acc = bias;
            #pragma unroll
            for (int c = 0; c < 8; ++c) acc += lu[r][c] * wu[c];
            int rn = row0 + r;
            int n = rn >> 10, t = rn & 1023;
            preU16[((size_t)t*NB + n)*256 + tid] = (_Float16)acc;
        }
    }
}

// -------------------------------------------------------------------------
// K2: backward scan, transposed MFMA, 8 blocks x 4 REAL batches (12 pad).
// Unrolled x2: prefetch ring in NAMED registers (no dynamic indexing ->
// no scratch, rule #20). Pad lanes load clamped batch (uniform control
// flow); stores exec-masked by act. 1 barrier/step.
// -------------------------------------------------------------------------
__global__ __launch_bounds__(256, 1) void k_bwscan(
    const _Float16* __restrict__ apre16, const float* __restrict__ wh,
    _Float16* __restrict__ hcell16)
{
    const int nb = blockIdx.x * 4;
    const int tid = threadIdx.x;
    const int w = tid >> 6, l = tid & 63;
    const int g = l >> 4, c = l & 15;
    __shared__ __align__(16) _Float16 Hl[2][16 * 128];

    f16x8 Af[2][4];
    #pragma unroll
    for (int jj = 0; jj < 2; ++jj)
        #pragma unroll
        for (int kt = 0; kt < 4; ++kt) {
            f16x8 v;
            #pragma unroll
            for (int i = 0; i < 8; ++i)
                v[i] = (_Float16)wh[(size_t)(kt*32 + g*8 + i)*128 + (2*w + jj)*16 + c];
            Af[jj][kt] = v;
        }

    for (int e = tid; e < 16 * 128; e += 256) Hl[0][e] = (_Float16)0.f;
    __syncthreads();

    const bool act = (c < 4);
    const int mybc = nb + (c & 3);     // clamped: uniform loads, pad lanes dup

    f16x4 apA0, apA1, apB0, apB1;
#define LOADB(d0v, d1v, tt) do { \
        if ((tt) >= 0) { \
            size_t ab = ((size_t)(tt)*NB + mybc)*128; \
            d0v = *(const f16x4*)&apre16[ab + (2*w + 0)*16 + g*4]; \
            d1v = *(const f16x4*)&apre16[ab + (2*w + 1)*16 + g*4]; \
        } else { d0v = (_Float16)0; d1v = (_Float16)0; } } while (0)

    LOADB(apA0, apA1, 1023);
    LOADB(apB0, apB1, 1022);

#define BWSTEP(cur, nxt, ap0, ap1, tt) do { \
        f16x8 b0 = *(const f16x8*)&Hl[cur][SWZ(c, 128, 0*32 + g*8)]; \
        f16x8 b1 = *(const f16x8*)&Hl[cur][SWZ(c, 128, 1*32 + g*8)]; \
        f16x8 b2 = *(const f16x8*)&Hl[cur][SWZ(c, 128, 2*32 + g*8)]; \
        f16x8 b3 = *(const f16x8*)&Hl[cur][SWZ(c, 128, 3*32 + g*8)]; \
        _Pragma("unroll") \
        for (int jj = 0; jj < 2; ++jj) { \
            f32x4 aA = {0.f,0.f,0.f,0.f}, aB = {0.f,0.f,0.f,0.f}; \
            aA = __builtin_amdgcn_mfma_f32_16x16x32_f16(Af[jj][0], b0, aA, 0, 0, 0); \
            aB = __builtin_amdgcn_mfma_f32_16x16x32_f16(Af[jj][1], b1, aB, 0, 0, 0); \
            aA = __builtin_amdgcn_mfma_f32_16x16x32_f16(Af[jj][2], b2, aA, 0, 0, 0); \
            aB = __builtin_amdgcn_mfma_f32_16x16x32_f16(Af[jj][3], b3, aB, 0, 0, 0); \
            f32x4 acc = aA + aB; \
            const f16x4 apv = (jj == 0) ? ap0 : ap1; \
            const int j0 = (2*w + jj)*16 + g*4; \
            f16x4 hh; \
            _Pragma("unroll") \
            for (int r = 0; r < 4; ++r) \
                hh[r] = (_Float16)fast_tanh(acc[r] + (float)apv[r]); \
            *(f16x4*)&Hl[nxt][SWZ(c, 128, j0)] = hh; \
            if (act) \
                *(f16x4*)&hcell16[((size_t)(tt)*NB + nb + c)*128 + j0] = hh; \
        } \
        bar_sync(); } while (0)

    for (int t = 1023; t > 0; t -= 2) {
        f16x4 n0a, n0b, n1a, n1b;
        LOADB(n0a, n0b, t - 2);
        BWSTEP(0, 1, apA0, apA1, t);
        LOADB(n1a, n1b, t - 3);
        BWSTEP(1, 0, apB0, apB1, t - 1);
        apA0 = n0a; apA1 = n0b;
        apB0 = n1a; apB1 = n1b;
    }
#undef BWSTEP
#undef LOADB
}

// -------------------------------------------------------------------------
// K3: b = hcell @ wo + bo; alpha16 = f16([b[:64], -softplus(b[64:])])
// -------------------------------------------------------------------------
__global__ __launch_bounds__(256) void k_alpha(
    const _Float16* __restrict__ hcell16, const float* __restrict__ wo,
    const float* __restrict__ bo, _Float16* __restrict__ alpha16)
{
    __shared__ float lhc[8][128];
    const int tid = threadIdx.x;
    const size_t base = (size_t)blockIdx.x * 8 * 128;
    {
        f16x4 hv = *(const f16x4*)&hcell16[base + tid*4];
        float4 f;
        #pragma unroll
        for (int r = 0; r < 4; ++r) ((float*)&f)[r] = (float)hv[r];
        ((float4*)&lhc[0][0])[tid] = f;
    }
    __syncthreads();

    const int j = tid & 127, rh = tid >> 7;
    float acc[4] = {0,0,0,0};
    for (int i = 0; i < 128; i += 4) {
        float w0 = wo[(i+0)*128 + j];
        float w1v = wo[(i+1)*128 + j];
        float w2v = wo[(i+2)*128 + j];
        float w3 = wo[(i+3)*128 + j];
        #pragma unroll
        for (int q = 0; q < 4; ++q) {
            float4 hv = *(const float4*)&lhc[rh*4+q][i];
            acc[q] += hv.x*w0 + hv.y*w1v + hv.z*w2v + hv.w*w3;
        }
    }
    float bias = bo[j];
    #pragma unroll
    for (int q = 0; q < 4; ++q) {
        float b = acc[q] + bias;
        float val = (j < 64) ? b : -softplus_f(b);
        alpha16[base + (size_t)(rh*4+q)*128 + j] = (_Float16)val;
    }
}

// -------------------------------------------------------------------------
// K4: forward scan, transposed MFMA, 8 blocks x 4 REAL batches (12 pad).
// Unrolled x2 with NAMED ring registers (no scratch). Pad lanes compute
// duplicate trajectories from clamped batch; out stores exec-masked.
// 2 barriers/step.
// -------------------------------------------------------------------------
__global__ __launch_bounds__(256, 1) void k_fwscan(
    const _Float16* __restrict__ alpha16, const _Float16* __restrict__ preU16,
    const float* __restrict__ dynw1, const float* __restrict__ dynw2,
    const float* __restrict__ dynb2, const float* __restrict__ qraw,
    const float* __restrict__ m0, const float* __restrict__ v0,
    float* __restrict__ out)
{
    const int nb = blockIdx.x * 4;
    const int tid = threadIdx.x;
    const int w = tid >> 6, l = tid & 63;
    const int g = l >> 4, c = l & 15;
    __shared__ __align__(16) _Float16 Mld[16 * 64];
    __shared__ __align__(16) _Float16 Hidl[16 * 256];

    f16x8 A1[4][2];
    #pragma unroll
    for (int hti = 0; hti < 4; ++hti)
        #pragma unroll
        for (int kt = 0; kt < 2; ++kt) {
            f16x8 v;
            #pragma unroll
            for (int i = 0; i < 8; ++i)
                v[i] = (_Float16)dynw1[(size_t)(kt*32 + g*8 + i)*256 + (w*4 + hti)*16 + c];
            A1[hti][kt] = v;
        }
    f16x8 A2[8];
    #pragma unroll
    for (int kt = 0; kt < 8; ++kt) {
        f16x8 v;
        #pragma unroll
        for (int i = 0; i < 8; ++i)
            v[i] = (_Float16)dynw2[(size_t)(kt*32 + g*8 + i)*64 + w*16 + c];
        A2[kt] = v;
    }

    const int d0 = w*16 + g*4;
    float Qv[4], b2v4[4], vreg[4];
    #pragma unroll
    for (int r = 0; r < 4; ++r) {
        Qv[r]   = softplus_f(qraw[d0 + r]);
        b2v4[r] = dynb2[d0 + r];
        vreg[r] = v0[d0 + r];
    }

    for (int e = tid; e < 1024; e += 256) {
        int b = e >> 6, dd = e & 63;
        Mld[SWZ(b, 64, dd)] = (_Float16)m0[dd];
    }
    __syncthreads();

    const bool act = (c < 4);
    const int mybc = nb + (c & 3);

    f16x4 hpA0, hpA1, hpA2, hpA3, a1A, a2A;
    f16x4 hpB0, hpB1, hpB2, hpB3, a1B, a2B;
#define LOADF(h0v, h1v, h2v, h3v, a1v, a2v, tt) do { \
        if ((tt) < T_LEN) { \
            size_t pb = ((size_t)(tt)*NB + mybc)*256; \
            h0v = *(const f16x4*)&preU16[pb + (w*4 + 0)*16 + g*4]; \
            h1v = *(const f16x4*)&preU16[pb + (w*4 + 1)*16 + g*4]; \
            h2v = *(const f16x4*)&preU16[pb + (w*4 + 2)*16 + g*4]; \
            h3v = *(const f16x4*)&preU16[pb + (w*4 + 3)*16 + g*4]; \
            size_t ab = ((size_t)(tt)*NB + mybc)*128; \
            a1v = *(const f16x4*)&alpha16[ab + d0]; \
            a2v = *(const f16x4*)&alpha16[ab + 64 + d0]; \
        } else { \
            h0v = (_Float16)0; h1v = (_Float16)0; h2v = (_Float16)0; h3v = (_Float16)0; \
            a1v = (_Float16)0; a2v = (_Float16)0; } } while (0)

    LOADF(hpA0, hpA1, hpA2, hpA3, a1A, a2A, 0);
    LOADF(hpB0, hpB1, hpB2, hpB3, a1B, a2B, 1);

#define FWSTEP(hp0v, hp1v, hp2v, hp3v, a1v, a2v, tt) do { \
        f16x8 bm0 = *(const f16x8*)&Mld[SWZ(c, 64, 0*32 + g*8)]; \
        f16x8 bm1 = *(const f16x8*)&Mld[SWZ(c, 64, 1*32 + g*8)]; \
        _Pragma("unroll") \
        for (int hti = 0; hti < 4; ++hti) { \
            f32x4 aA = {0.f,0.f,0.f,0.f}, aB = {0.f,0.f,0.f,0.f}; \
            aA = __builtin_amdgcn_mfma_f32_16x16x32_f16(A1[hti][0], bm0, aA, 0, 0, 0); \
            aB = __builtin_amdgcn_mfma_f32_16x16x32_f16(A1[hti][1], bm1, aB, 0, 0, 0); \
            f32x4 acc = aA + aB; \
            const f16x4 hpv = (hti == 0) ? hp0v : (hti == 1) ? hp1v : (hti == 2) ? hp2v : hp3v; \
            const int h0 = (w*4 + hti)*16 + g*4; \
            f16x4 hh; \
            _Pragma("unroll") \
            for (int r = 0; r < 4; ++r) \
                hh[r] = (_Float16)fast_tanh((float)hpv[r] + acc[r]); \
            *(f16x4*)&Hidl[SWZ(c, 256, h0)] = hh; \
        } \
        bar_sync(); \
        f32x4 aA = {0.f,0.f,0.f,0.f}, aB = {0.f,0.f,0.f,0.f}; \
        _Pragma("unroll") \
        for (int kt = 0; kt < 8; kt += 2) { \
            f16x8 h0v = *(const f16x8*)&Hidl[SWZ(c, 256, kt*32 + g*8)]; \
            f16x8 h1v = *(const f16x8*)&Hidl[SWZ(c, 256, (kt+1)*32 + g*8)]; \
            aA = __builtin_amdgcn_mfma_f32_16x16x32_f16(A2[kt],   h0v, aA, 0, 0, 0); \
            aB = __builtin_amdgcn_mfma_f32_16x16x32_f16(A2[kt+1], h1v, aB, 0, 0, 0); \
        } \
        f32x4 acc2 = aA + aB; \
        float4 oms, ovs, omp, ovp; \
        f16x4 mm; \
        _Pragma("unroll") \
        for (int r = 0; r < 4; ++r) { \
            float m_p = acc2[r] + b2v4[r]; \
            float v_p = vreg[r] + Qv[r]; \
            float rvp = __builtin_amdgcn_rcpf(v_p); \
            float e1 = m_p * rvp + (float)a1v[r]; \
            float e2 = (float)a2v[r] - 0.5f * rvp; \
            float v_s = -0.5f * __builtin_amdgcn_rcpf(e2); \
            float m_s = v_s * e1; \
            vreg[r] = v_s; \
            ((float*)&oms)[r] = m_s; ((float*)&ovs)[r] = v_s; \
            ((float*)&omp)[r] = m_p; ((float*)&ovp)[r] = v_p; \
            mm[r] = (_Float16)m_s; \
        } \
        *(f16x4*)&Mld[SWZ(c, 64, d0)] = mm; \
        if (act) { \
            size_t ob = ((size_t)(nb + c)*T_LEN + (tt))*256; \
            *(float4*)&out[ob + d0]        = oms; \
            *(float4*)&out[ob + 64 + d0]   = ovs; \
            *(float4*)&out[ob + 128 + d0]  = omp; \
            *(float4*)&out[ob + 192 + d0]  = ovp; \
        } \
        bar_sync(); } while (0)

    for (int t = 0; t < T_LEN; t += 2) {
        f16x4 n0, n1, n2, n3, na1, na2;
        LOADF(n0, n1, n2, n3, na1, na2, t + 2);
        FWSTEP(hpA0, hpA1, hpA2, hpA3, a1A, a2A, t);
        f16x4 m0v, m1v, m2v, m3v, ma1, ma2;
        LOADF(m0v, m1v, m2v, m3v, ma1, ma2, t + 3);
        FWSTEP(hpB0, hpB1, hpB2, hpB3, a1B, a2B, t + 1);
        hpA0 = n0; hpA1 = n1; hpA2 = n2; hpA3 = n3; a1A = na1; a2A = na2;
        hpB0 = m0v; hpB1 = m1v; hpB2 = m2v; hpB3 = m3v; a1B = ma1; a2B = ma2;
    }
#undef FWSTEP
#undef LOADF
}

// -------------------------------------------------------------------------
extern "C" void kernel_launch(void* const* d_in, const int* in_sizes, int n_in,
                              void* d_out, int out_size, void* d_ws, size_t ws_size,
                              hipStream_t stream) {
    const float* y      = (const float*)d_in[1];
    const float* u      = (const float*)d_in[2];
    const float* enc_w1 = (const float*)d_in[3];
    const float* enc_b1 = (const float*)d_in[4];
    const float* enc_w2 = (const float*)d_in[5];
    const float* enc_b2 = (const float*)d_in[6];
    const float* bw_wa  = (const float*)d_in[7];
    const float* bw_wh  = (const float*)d_in[8];
    const float* bw_b   = (const float*)d_in[9];
    const float* bw_wo  = (const float*)d_in[10];
    const float* bw_bo  = (const float*)d_in[11];
    const float* dyn_w1 = (const float*)d_in[12];
    const float* dyn_b1 = (const float*)d_in[13];
    const float* dyn_w2 = (const float*)d_in[14];
    const float* dyn_b2 = (const float*)d_in[15];
    const float* q_raw  = (const float*)d_in[16];
    const float* m0     = (const float*)d_in[17];
    const float* v0     = (const float*)d_in[18];
    float* out = (float*)d_out;

    // workspace (f16): apre/alpha alias 8MB, hcell 8MB, preU 16MB
    _Float16* ws16 = (_Float16*)d_ws;
    _Float16* apre16  = ws16;                    // [T*NB][128]
    _Float16* hcell16 = ws16 + 4194304;          // [T*NB][128]
    _Float16* alpha16 = ws16;                    // aliases apre
    _Float16* preU16  = ws16 + 2 * 4194304;      // [T*NB][256]

    k_encoder<<<4096, 256, 0, stream>>>(y, u, enc_w1, enc_b1, enc_w2, enc_b2,
                                        bw_wa, bw_b, dyn_w1, dyn_b1, apre16, preU16);
    k_bwscan<<<8, 256, 0, stream>>>(apre16, bw_wh, hcell16);
    k_alpha<<<4096, 256, 0, stream>>>(hcell16, bw_wo, bw_bo, alpha16);
    k_fwscan<<<8, 256, 0, stream>>>(alpha16, preU16, dyn_w1, dyn_w2, dyn_b2,
                                    q_raw, m0, v0, out);
}

// Round 12
// 1986.052 us; speedup vs baseline: 9.5312x; 1.1697x over previous
//
#include <hip/hip_runtime.h>
#include <math.h>

// XFADS: N=32, T=1024, D_OBS=128, D_Z=64, D_U=8, H_ENC=256, H_BW=128, H_DYN=256, D_A=128
#define T_LEN 1024
#define NB 32

typedef _Float16 f16x8 __attribute__((ext_vector_type(8)));
typedef _Float16 f16x4 __attribute__((ext_vector_type(4)));
typedef float f32x4 __attribute__((ext_vector_type(4)));

__device__ __forceinline__ float softplus_f(float x) {
    return fmaxf(x, 0.f) + log1pf(expf(-fabsf(x)));
}

__device__ __forceinline__ float fast_tanh(float x) {
    float e = __builtin_amdgcn_exp2f(x * 2.88539008177792681472f);
    float r = __builtin_amdgcn_rcpf(1.f + e);
    return 1.f - 2.f * r;
}

// raw barrier: drain LDS ops only; global prefetches stay in flight (T4 pattern)
__device__ __forceinline__ void bar_sync() {
    asm volatile("s_waitcnt lgkmcnt(0)" ::: "memory");
    __builtin_amdgcn_s_barrier();
    asm volatile("" ::: "memory");
}

// swizzled f16-row addressing: row b (stride R f16), element idx.
#define SWZ(b, R, idx) ((b)*(R) + ((((idx) >> 3) ^ ((b) & 7)) << 3) + ((idx) & 7))

// -------------------------------------------------------------------------
// K1: encoder (unchanged from r11)
// -------------------------------------------------------------------------
__global__ __launch_bounds__(256) void k_encoder(
    const float* __restrict__ y, const float* __restrict__ u,
    const float* __restrict__ w1, const float* __restrict__ b1,
    const float* __restrict__ w2, const float* __restrict__ b2,
    const float* __restrict__ wa, const float* __restrict__ bb,
    const float* __restrict__ dynw1, const float* __restrict__ dynb1,
    _Float16* __restrict__ apre16, _Float16* __restrict__ preU16)
{
    __shared__ float ly[8][128];
    __shared__ float lh[8][256];
    __shared__ float la[8][128];
    __shared__ float lu[8][8];
    const int tid = threadIdx.x;
    const int row0 = blockIdx.x * 8;

    ((float4*)&ly[0][0])[tid] = ((const float4*)(y + (size_t)row0 * 128))[tid];
    if (tid < 16)
        ((float4*)&lu[0][0])[tid] = ((const float4*)(u + (size_t)row0 * 8))[tid];
    __syncthreads();

    {
        float acc[8] = {0,0,0,0,0,0,0,0};
        for (int i = 0; i < 128; i += 4) {
            float w0 = w1[(i+0)*256 + tid];
            float w1v = w1[(i+1)*256 + tid];
            float w2v = w1[(i+2)*256 + tid];
            float w3 = w1[(i+3)*256 + tid];
            #pragma unroll
            for (int r = 0; r < 8; ++r) {
                float4 yv = *(const float4*)&ly[r][i];
                acc[r] += yv.x*w0 + yv.y*w1v + yv.z*w2v + yv.w*w3;
            }
        }
        float bias = b1[tid];
        #pragma unroll
        for (int r = 0; r < 8; ++r) lh[r][tid] = fast_tanh(acc[r] + bias);
    }
    __syncthreads();

    {
        const int d = tid & 127, rh = tid >> 7;
        float acc[4] = {0,0,0,0};
        for (int i = 0; i < 256; i += 4) {
            float w0 = w2[(i+0)*128 + d];
            float w1v = w2[(i+1)*128 + d];
            float w2v = w2[(i+2)*128 + d];
            float w3 = w2[(i+3)*128 + d];
            #pragma unroll
            for (int q = 0; q < 4; ++q) {
                float4 hv = *(const float4*)&lh[rh*4+q][i];
                acc[q] += hv.x*w0 + hv.y*w1v + hv.z*w2v + hv.w*w3;
            }
        }
        float bias = b2[d];
        #pragma unroll
        for (int q = 0; q < 4; ++q) la[rh*4+q][d] = acc[q] + bias;
    }
    __syncthreads();

    {
        const int j = tid & 127, rh = tid >> 7;
        float acc[4] = {0,0,0,0};
        for (int i = 0; i < 128; i += 4) {
            float w0 = wa[(i+0)*128 + j];
            float w1v = wa[(i+1)*128 + j];
            float w2v = wa[(i+2)*128 + j];
            float w3 = wa[(i+3)*128 + j];
            #pragma unroll
            for (int q = 0; q < 4; ++q) {
                float4 av = *(const float4*)&la[rh*4+q][i];
                acc[q] += av.x*w0 + av.y*w1v + av.z*w2v + av.w*w3;
            }
        }
        float bias = bb[j];
        #pragma unroll
        for (int q = 0; q < 4; ++q) {
            int rn = row0 + rh*4 + q;
            int n = rn >> 10, t = rn & 1023;
            apre16[((size_t)t*NB + n)*128 + j] = (_Float16)(acc[q] + bias);
        }
    }

    {
        float wu[8];
        #pragma unroll
        for (int cc = 0; cc < 8; ++cc) wu[cc] = dynw1[(64 + cc)*256 + tid];
        float bias = dynb1[tid];
        #pragma unroll
        for (int r = 0; r < 8; ++r) {
            float acc = bias;
            #pragma unroll
            for (int cc = 0; cc < 8; ++cc) acc += lu[r][cc] * wu[cc];
            int rn = row0 + r;
            int n = rn >> 10, t = rn & 1023;
            preU16[((size_t)t*NB + n)*256 + tid] = (_Float16)acc;
        }
    }
}

// -------------------------------------------------------------------------
// K2: backward scan. 4 blocks x 8 real batches, 1024 thr (16 waves, 4/SIMD).
// H'^T = tanh(apre^T + Wh^T @ H^T). Wave task: (j-tile = w&7, k-half = w>>3)
// -> partial f32x4 to padded LDS (stride 17). Epilogue: thread (be,je) sums
// 2 partials x 2 j's, tanh, writes H dbuf + hcell16. 2 barriers/step.
// Pad cols 8-15 carry isolated garbage (GEMM column independence).
// -------------------------------------------------------------------------
__global__ __launch_bounds__(1024, 1) void k_bwscan(
    const _Float16* __restrict__ apre16, const float* __restrict__ wh,
    _Float16* __restrict__ hcell16)
{
    const int nb = blockIdx.x * 8;
    const int tid = threadIdx.x;
    const int w = tid >> 6, l = tid & 63;
    const int g = l >> 4, c = l & 15;
    const int be = tid >> 6, je = tid & 63;
    const int jt = w & 7, kh = w >> 3;
    __shared__ __align__(16) _Float16 Hl[2][16 * 128];
    __shared__ float PPb[4352];

    f16x8 Af0, Af1;
    #pragma unroll
    for (int i = 0; i < 8; ++i) {
        Af0[i] = (_Float16)wh[(size_t)((kh*2+0)*32 + g*8 + i)*128 + jt*16 + c];
        Af1[i] = (_Float16)wh[(size_t)((kh*2+1)*32 + g*8 + i)*128 + jt*16 + c];
    }

    Hl[0][tid] = (_Float16)0.f;
    Hl[0][tid + 1024] = (_Float16)0.f;
    __syncthreads();

    const int ae = nb + (be & 7);      // clamped batch for loads
    const bool act = (be < 8);

    _Float16 apA0, apA1, apB0, apB1;
#define LOADB(d0v, d1v, tt) do { \
        if ((tt) >= 0) { \
            size_t ab = ((size_t)(tt)*NB + ae)*128; \
            d0v = apre16[ab + je]; \
            d1v = apre16[ab + 64 + je]; \
        } else { d0v = (_Float16)0.f; d1v = (_Float16)0.f; } } while (0)

    LOADB(apA0, apA1, 1023);
    LOADB(apB0, apB1, 1022);

#define BWSTEP(cur, nxt, ap0, ap1, tt) do { \
        f16x8 hb0 = *(const f16x8*)&Hl[cur][SWZ(c, 128, (kh*2+0)*32 + g*8)]; \
        f16x8 hb1 = *(const f16x8*)&Hl[cur][SWZ(c, 128, (kh*2+1)*32 + g*8)]; \
        f32x4 p = {0.f,0.f,0.f,0.f}; \
        p = __builtin_amdgcn_mfma_f32_16x16x32_f16(Af0, hb0, p, 0, 0, 0); \
        p = __builtin_amdgcn_mfma_f32_16x16x32_f16(Af1, hb1, p, 0, 0, 0); \
        _Pragma("unroll") \
        for (int r = 0; r < 4; ++r) \
            PPb[(size_t)(kh*128 + jt*16 + g*4 + r)*17 + c] = p[r]; \
        bar_sync(); \
        float s0 = PPb[(size_t)(je)*17 + be] + PPb[(size_t)(128 + je)*17 + be] + (float)ap0; \
        float s1 = PPb[(size_t)(64 + je)*17 + be] + PPb[(size_t)(192 + je)*17 + be] + (float)ap1; \
        float hc0 = fast_tanh(s0); \
        float hc1 = fast_tanh(s1); \
        Hl[nxt][SWZ(be, 128, je)] = (_Float16)hc0; \
        Hl[nxt][SWZ(be, 128, 64 + je)] = (_Float16)hc1; \
        if (act) { \
            size_t hb = ((size_t)(tt)*NB + nb + be)*128; \
            hcell16[hb + je] = (_Float16)hc0; \
            hcell16[hb + 64 + je] = (_Float16)hc1; \
        } \
        bar_sync(); } while (0)

    for (int t = 1023; t > 0; t -= 2) {
        _Float16 n0a, n0b, n1a, n1b;
        LOADB(n0a, n0b, t - 2);
        BWSTEP(0, 1, apA0, apA1, t);
        LOADB(n1a, n1b, t - 3);
        BWSTEP(1, 0, apB0, apB1, t - 1);
        apA0 = n0a; apA1 = n0b;
        apB0 = n1a; apB1 = n1b;
    }
#undef BWSTEP
#undef LOADB
}

// -------------------------------------------------------------------------
// K3: alpha (unchanged from r11)
// -------------------------------------------------------------------------
__global__ __launch_bounds__(256) void k_alpha(
    const _Float16* __restrict__ hcell16, const float* __restrict__ wo,
    const float* __restrict__ bo, _Float16* __restrict__ alpha16)
{
    __shared__ float lhc[8][128];
    const int tid = threadIdx.x;
    const size_t base = (size_t)blockIdx.x * 8 * 128;
    {
        f16x4 hv = *(const f16x4*)&hcell16[base + tid*4];
        float4 f;
        #pragma unroll
        for (int r = 0; r < 4; ++r) ((float*)&f)[r] = (float)hv[r];
        ((float4*)&lhc[0][0])[tid] = f;
    }
    __syncthreads();

    const int j = tid & 127, rh = tid >> 7;
    float acc[4] = {0,0,0,0};
    for (int i = 0; i < 128; i += 4) {
        float w0 = wo[(i+0)*128 + j];
        float w1v = wo[(i+1)*128 + j];
        float w2v = wo[(i+2)*128 + j];
        float w3 = wo[(i+3)*128 + j];
        #pragma unroll
        for (int q = 0; q < 4; ++q) {
            float4 hv = *(const float4*)&lhc[rh*4+q][i];
            acc[q] += hv.x*w0 + hv.y*w1v + hv.z*w2v + hv.w*w3;
        }
    }
    float bias = bo[j];
    #pragma unroll
    for (int q = 0; q < 4; ++q) {
        float b = acc[q] + bias;
        float val = (j < 64) ? b : -softplus_f(b);
        alpha16[base + (size_t)(rh*4+q)*128 + j] = (_Float16)val;
    }
}

// -------------------------------------------------------------------------
// K4: forward scan. 4 blocks x 8 real batches, 1024 thr (16 waves, 4/SIMD).
// G1: HID^T = tanh(preU^T + W1m^T @ M^T) — wave w owns h-tile w (k-chain 2).
// G2: PRED^T partials — wave w owns (d-tile = w&3, k-quarter = w>>2),
//     2-chain -> padded LDS. Epilogue: thread (be,de) sums 4 partials,
//     posterior update, writes Mld + out. 3 barriers/step.
// -------------------------------------------------------------------------
__global__ __launch_bounds__(1024, 1) void k_fwscan(
    const _Float16* __restrict__ alpha16, const _Float16* __restrict__ preU16,
    const float* __restrict__ dynw1, const float* __restrict__ dynw2,
    const float* __restrict__ dynb2, const float* __restrict__ qraw,
    const float* __restrict__ m0, const float* __restrict__ v0,
    float* __restrict__ out)
{
    const int nb = blockIdx.x * 8;
    const int tid = threadIdx.x;
    const int w = tid >> 6, l = tid & 63;
    const int g = l >> 4, c = l & 15;
    const int be = tid >> 6, de = tid & 63;
    const int dt = w & 3, kq = w >> 2;
    __shared__ __align__(16) _Float16 Mld[16 * 64];
    __shared__ __align__(16) _Float16 Hidl[16 * 256];
    __shared__ float PP[4352];

    f16x8 A1k0, A1k1, A2k0, A2k1;
    #pragma unroll
    for (int i = 0; i < 8; ++i) {
        A1k0[i] = (_Float16)dynw1[(size_t)(0*32 + g*8 + i)*256 + w*16 + c];
        A1k1[i] = (_Float16)dynw1[(size_t)(1*32 + g*8 + i)*256 + w*16 + c];
        A2k0[i] = (_Float16)dynw2[(size_t)((kq*2+0)*32 + g*8 + i)*64 + dt*16 + c];
        A2k1[i] = (_Float16)dynw2[(size_t)((kq*2+1)*32 + g*8 + i)*64 + dt*16 + c];
    }

    const int ae = nb + (be & 7);      // clamped batch (epilogue loads)
    const int cbv = nb + (c & 7);      // clamped batch (G1 preU loads)
    const bool act = (be < 8);

    const float Qv  = softplus_f(qraw[de]);
    const float b2v = dynb2[de];
    float vreg = v0[de];

    {   // init M (all 16 rows; pad rows harmless)
        int b = tid >> 6, dd = tid & 63;
        Mld[SWZ(b, 64, dd)] = (_Float16)m0[dd];
    }
    __syncthreads();

    f16x4 hpA, hpB;
    _Float16 a1A, a2A, a1B, a2B;
#define LOADF(hpv, a1v, a2v, tt) do { \
        if ((tt) < T_LEN) { \
            hpv = *(const f16x4*)&preU16[((size_t)(tt)*NB + cbv)*256 + w*16 + g*4]; \
            size_t ab = ((size_t)(tt)*NB + ae)*128; \
            a1v = alpha16[ab + de]; \
            a2v = alpha16[ab + 64 + de]; \
        } else { hpv = (_Float16)0.f; a1v = (_Float16)0.f; a2v = (_Float16)0.f; } } while (0)

    LOADF(hpA, a1A, a2A, 0);
    LOADF(hpB, a1B, a2B, 1);

#define FWSTEP(hpv, a1v, a2v, tt) do { \
        /* G1: wave w -> h-tile w */ \
        f16x8 bm0 = *(const f16x8*)&Mld[SWZ(c, 64, g*8)]; \
        f16x8 bm1 = *(const f16x8*)&Mld[SWZ(c, 64, 32 + g*8)]; \
        f32x4 acc = {0.f,0.f,0.f,0.f}; \
        acc = __builtin_amdgcn_mfma_f32_16x16x32_f16(A1k0, bm0, acc, 0, 0, 0); \
        acc = __builtin_amdgcn_mfma_f32_16x16x32_f16(A1k1, bm1, acc, 0, 0, 0); \
        f16x4 hh; \
        _Pragma("unroll") \
        for (int r = 0; r < 4; ++r) \
            hh[r] = (_Float16)fast_tanh((float)hpv[r] + acc[r]); \
        *(f16x4*)&Hidl[SWZ(c, 256, w*16 + g*4)] = hh; \
        bar_sync(); \
        /* G2: wave (dt, kq) partial */ \
        f16x8 hb0 = *(const f16x8*)&Hidl[SWZ(c, 256, (kq*2+0)*32 + g*8)]; \
        f16x8 hb1 = *(const f16x8*)&Hidl[SWZ(c, 256, (kq*2+1)*32 + g*8)]; \
        f32x4 p = {0.f,0.f,0.f,0.f}; \
        p = __builtin_amdgcn_mfma_f32_16x16x32_f16(A2k0, hb0, p, 0, 0, 0); \
        p = __builtin_amdgcn_mfma_f32_16x16x32_f16(A2k1, hb1, p, 0, 0, 0); \
        _Pragma("unroll") \
        for (int r = 0; r < 4; ++r) \
            PP[(size_t)(kq*64 + dt*16 + g*4 + r)*17 + c] = p[r]; \
        bar_sync(); \
        /* epilogue: thread (be,de) */ \
        float m_p = PP[(size_t)(0*64 + de)*17 + be] + PP[(size_t)(1*64 + de)*17 + be] \
                  + PP[(size_t)(2*64 + de)*17 + be] + PP[(size_t)(3*64 + de)*17 + be] + b2v; \
        float v_p = vreg + Qv; \
        float rvp = __builtin_amdgcn_rcpf(v_p); \
        float e1 = m_p * rvp + (float)a1v; \
        float e2 = (float)a2v - 0.5f * rvp; \
        float v_s = -0.5f * __builtin_amdgcn_rcpf(e2); \
        float m_s = v_s * e1; \
        vreg = v_s; \
        if (act) { \
            Mld[SWZ(be, 64, de)] = (_Float16)m_s; \
            size_t ob = ((size_t)(nb + be)*T_LEN + (tt))*256; \
            out[ob + de]        = m_s; \
            out[ob + 64 + de]   = v_s; \
            out[ob + 128 + de]  = m_p; \
            out[ob + 192 + de]  = v_p; \
        } \
        bar_sync(); } while (0)

    for (int t = 0; t < T_LEN; t += 2) {
        f16x4 nhp; _Float16 na1, na2;
        LOADF(nhp, na1, na2, t + 2);
        FWSTEP(hpA, a1A, a2A, t);
        f16x4 mhp; _Float16 ma1, ma2;
        LOADF(mhp, ma1, ma2, t + 3);
        FWSTEP(hpB, a1B, a2B, t + 1);
        hpA = nhp; a1A = na1; a2A = na2;
        hpB = mhp; a1B = ma1; a2B = ma2;
    }
#undef FWSTEP
#undef LOADF
}

// -------------------------------------------------------------------------
extern "C" void kernel_launch(void* const* d_in, const int* in_sizes, int n_in,
                              void* d_out, int out_size, void* d_ws, size_t ws_size,
                              hipStream_t stream) {
    const float* y      = (const float*)d_in[1];
    const float* u      = (const float*)d_in[2];
    const float* enc_w1 = (const float*)d_in[3];
    const float* enc_b1 = (const float*)d_in[4];
    const float* enc_w2 = (const float*)d_in[5];
    const float* enc_b2 = (const float*)d_in[6];
    const float* bw_wa  = (const float*)d_in[7];
    const float* bw_wh  = (const float*)d_in[8];
    const float* bw_b   = (const float*)d_in[9];
    const float* bw_wo  = (const float*)d_in[10];
    const float* bw_bo  = (const float*)d_in[11];
    const float* dyn_w1 = (const float*)d_in[12];
    const float* dyn_b1 = (const float*)d_in[13];
    const float* dyn_w2 = (const float*)d_in[14];
    const float* dyn_b2 = (const float*)d_in[15];
    const float* q_raw  = (const float*)d_in[16];
    const float* m0     = (const float*)d_in[17];
    const float* v0     = (const float*)d_in[18];
    float* out = (float*)d_out;

    // workspace (f16): apre/alpha alias 8MB, hcell 8MB, preU 16MB
    _Float16* ws16 = (_Float16*)d_ws;
    _Float16* apre16  = ws16;                    // [T*NB][128]
    _Float16* hcell16 = ws16 + 4194304;          // [T*NB][128]
    _Float16* alpha16 = ws16;                    // aliases apre
    _Float16* preU16  = ws16 + 2 * 4194304;      // [T*NB][256]

    k_encoder<<<4096, 256, 0, stream>>>(y, u, enc_w1, enc_b1, enc_w2, enc_b2,
                                        bw_wa, bw_b, dyn_w1, dyn_b1, apre16, preU16);
    k_bwscan<<<4, 1024, 0, stream>>>(apre16, bw_wh, hcell16);
    k_alpha<<<4096, 256, 0, stream>>>(hcell16, bw_wo, bw_bo, alpha16);
    k_fwscan<<<4, 1024, 0, stream>>>(alpha16, preU16, dyn_w1, dyn_w2, dyn_b2,
                                     q_raw, m0, v0, out);
}

// Round 13
// 1267.637 us; speedup vs baseline: 14.9329x; 1.5667x over previous
//
#include <hip/hip_runtime.h>
#include <math.h>

// XFADS: N=32, T=1024, D_OBS=128, D_Z=64, D_U=8, H_ENC=256, H_BW=128, H_DYN=256, D_A=128
#define T_LEN 1024
#define NB 32

typedef _Float16 h2 __attribute__((ext_vector_type(2)));

__device__ __forceinline__ h2 f2h2(float f) { return __builtin_bit_cast(h2, f); }

__device__ __forceinline__ float dot2(h2 a, h2 b, float c) {
#if __has_builtin(__builtin_amdgcn_fdot2)
    return __builtin_amdgcn_fdot2(a, b, c, false);
#else
    return fmaf((float)a[0], (float)b[0], fmaf((float)a[1], (float)b[1], c));
#endif
}

// cross-lane add via DPP (VALU pipe, not DS): ctrl must be a literal.
// 0xB1 = quad_perm(1,0,3,2) = xor1 ; 0x4E = quad_perm(2,3,0,1) = xor2 ;
// 0x124 = ROW_ROR:4 ; 0x128 = ROW_ROR:8 (rotation-allreduce within 16-row).
#define DPP_ADD(v, ctrl) do { \
    int _xi = __builtin_bit_cast(int, v); \
    int _yi = __builtin_amdgcn_update_dpp(_xi, _xi, (ctrl), 0xF, 0xF, true); \
    v += __builtin_bit_cast(float, _yi); } while (0)

__device__ __forceinline__ float softplus_f(float x) {
    return fmaxf(x, 0.f) + log1pf(expf(-fabsf(x)));
}

__device__ __forceinline__ float fast_tanh(float x) {
    float e = __builtin_amdgcn_exp2f(x * 2.88539008177792681472f);
    float r = __builtin_amdgcn_rcpf(1.f + e);
    return 1.f - 2.f * r;
}

// raw barrier: drain LDS ops only; global prefetches stay in flight
__device__ __forceinline__ void bar_sync() {
    asm volatile("s_waitcnt lgkmcnt(0)" ::: "memory");
    __builtin_amdgcn_s_barrier();
    asm volatile("" ::: "memory");
}

// -------------------------------------------------------------------------
// K1: encoder (r6 verbatim)
// -------------------------------------------------------------------------
__global__ __launch_bounds__(256) void k_encoder(
    const float* __restrict__ y, const float* __restrict__ u,
    const float* __restrict__ w1, const float* __restrict__ b1,
    const float* __restrict__ w2, const float* __restrict__ b2,
    const float* __restrict__ wa, const float* __restrict__ bb,
    const float* __restrict__ dynw1, const float* __restrict__ dynb1,
    float* __restrict__ apre, float* __restrict__ preU)
{
    __shared__ float ly[8][128];
    __shared__ float lh[8][256];
    __shared__ float la[8][128];
    __shared__ float lu[8][8];
    const int tid = threadIdx.x;
    const int row0 = blockIdx.x * 8;

    ((float4*)&ly[0][0])[tid] = ((const float4*)(y + (size_t)row0 * 128))[tid];
    if (tid < 16)
        ((float4*)&lu[0][0])[tid] = ((const float4*)(u + (size_t)row0 * 8))[tid];
    __syncthreads();

    {
        float acc[8] = {0,0,0,0,0,0,0,0};
        for (int i = 0; i < 128; i += 4) {
            float w0 = w1[(i+0)*256 + tid];
            float w1v = w1[(i+1)*256 + tid];
            float w2v = w1[(i+2)*256 + tid];
            float w3 = w1[(i+3)*256 + tid];
            #pragma unroll
            for (int r = 0; r < 8; ++r) {
                float4 yv = *(const float4*)&ly[r][i];
                acc[r] += yv.x*w0 + yv.y*w1v + yv.z*w2v + yv.w*w3;
            }
        }
        float bias = b1[tid];
        #pragma unroll
        for (int r = 0; r < 8; ++r) lh[r][tid] = fast_tanh(acc[r] + bias);
    }
    __syncthreads();

    {
        const int d = tid & 127, rh = tid >> 7;
        float acc[4] = {0,0,0,0};
        for (int i = 0; i < 256; i += 4) {
            float w0 = w2[(i+0)*128 + d];
            float w1v = w2[(i+1)*128 + d];
            float w2v = w2[(i+2)*128 + d];
            float w3 = w2[(i+3)*128 + d];
            #pragma unroll
            for (int q = 0; q < 4; ++q) {
                float4 hv = *(const float4*)&lh[rh*4+q][i];
                acc[q] += hv.x*w0 + hv.y*w1v + hv.z*w2v + hv.w*w3;
            }
        }
        float bias = b2[d];
        #pragma unroll
        for (int q = 0; q < 4; ++q) la[rh*4+q][d] = acc[q] + bias;
    }
    __syncthreads();

    {
        const int j = tid & 127, rh = tid >> 7;
        float acc[4] = {0,0,0,0};
        for (int i = 0; i < 128; i += 4) {
            float w0 = wa[(i+0)*128 + j];
            float w1v = wa[(i+1)*128 + j];
            float w2v = wa[(i+2)*128 + j];
            float w3 = wa[(i+3)*128 + j];
            #pragma unroll
            for (int q = 0; q < 4; ++q) {
                float4 av = *(const float4*)&la[rh*4+q][i];
                acc[q] += av.x*w0 + av.y*w1v + av.z*w2v + av.w*w3;
            }
        }
        float bias = bb[j];
        #pragma unroll
        for (int q = 0; q < 4; ++q) {
            int rn = row0 + rh*4 + q;
            int n = rn >> 10, t = rn & 1023;
            apre[((size_t)t*NB + n)*128 + j] = acc[q] + bias;
        }
    }

    {
        float wu[8];
        #pragma unroll
        for (int c = 0; c < 8; ++c) wu[c] = dynw1[(64 + c)*256 + tid];
        float bias = dynb1[tid];
        #pragma unroll
        for (int r = 0; r < 8; ++r) {
            float acc = bias;
            #pragma unroll
            for (int c = 0; c < 8; ++c) acc += lu[r][c] * wu[c];
            int rn = row0 + r;
            int n = rn >> 10, t = rn & 1023;
            preU[((size_t)t*NB + n)*256 + tid] = acc;
        }
    }
}

// -------------------------------------------------------------------------
// K2: backward RNN scan. 512 threads, 1 batch/block, grid NB.
// thread (j = tid>>2, p = tid&3): 32-MAC partial (16 dot2) of column j over
// h_f16[p*32..+31]; quad-DPP allreduce (xor1+xor2, VALU pipe, zero DS
// shuffles). State f16 in LDS. ONE barrier/step; prefetch distance 2.
// -------------------------------------------------------------------------
__global__ __launch_bounds__(512, 1) void k_bwscan(
    const float* __restrict__ apre, const float* __restrict__ wh,
    float* __restrict__ hcell)
{
    const int n = blockIdx.x;
    const int tid = threadIdx.x;
    const int j = tid >> 2, p = tid & 3;
    __shared__ _Float16 h[2][128];

    // 32 weights Wh[p*32+k][j], k=0..31, packed into 16 h2 regs
    h2 w0, w1, w2, w3, w4, w5, w6, w7, w8, w9, w10, w11, w12, w13, w14, w15;
    {
        const float* s = wh + (size_t)(p * 32) * 128 + j;
        w0  = h2{(_Float16)s[0*128],  (_Float16)s[1*128]};
        w1  = h2{(_Float16)s[2*128],  (_Float16)s[3*128]};
        w2  = h2{(_Float16)s[4*128],  (_Float16)s[5*128]};
        w3  = h2{(_Float16)s[6*128],  (_Float16)s[7*128]};
        w4  = h2{(_Float16)s[8*128],  (_Float16)s[9*128]};
        w5  = h2{(_Float16)s[10*128], (_Float16)s[11*128]};
        w6  = h2{(_Float16)s[12*128], (_Float16)s[13*128]};
        w7  = h2{(_Float16)s[14*128], (_Float16)s[15*128]};
        w8  = h2{(_Float16)s[16*128], (_Float16)s[17*128]};
        w9  = h2{(_Float16)s[18*128], (_Float16)s[19*128]};
        w10 = h2{(_Float16)s[20*128], (_Float16)s[21*128]};
        w11 = h2{(_Float16)s[22*128], (_Float16)s[23*128]};
        w12 = h2{(_Float16)s[24*128], (_Float16)s[25*128]};
        w13 = h2{(_Float16)s[26*128], (_Float16)s[27*128]};
        w14 = h2{(_Float16)s[28*128], (_Float16)s[29*128]};
        w15 = h2{(_Float16)s[30*128], (_Float16)s[31*128]};
    }

    if (tid < 128) h[0][tid] = (_Float16)0.f;
    __syncthreads();

    float apA = apre[((size_t)1023*NB + n)*128 + j];
    float apB = apre[((size_t)1022*NB + n)*128 + j];

#define BWSTEP(cur, nxt, apv, tt) do { \
        const _Float16* hb = &h[cur][p*32]; \
        float4 r0 = *(const float4*)hb; \
        float4 r1 = *(const float4*)(hb + 8); \
        float4 r2 = *(const float4*)(hb + 16); \
        float4 r3 = *(const float4*)(hb + 24); \
        float c0 = dot2(f2h2(r0.x), w0, 0.f); \
        float c1 = dot2(f2h2(r0.y), w1, 0.f); \
        float c2 = dot2(f2h2(r0.z), w2, 0.f); \
        float c3 = dot2(f2h2(r0.w), w3, 0.f); \
        c0 = dot2(f2h2(r1.x), w4, c0); \
        c1 = dot2(f2h2(r1.y), w5, c1); \
        c2 = dot2(f2h2(r1.z), w6, c2); \
        c3 = dot2(f2h2(r1.w), w7, c3); \
        c0 = dot2(f2h2(r2.x), w8, c0); \
        c1 = dot2(f2h2(r2.y), w9, c1); \
        c2 = dot2(f2h2(r2.z), w10, c2); \
        c3 = dot2(f2h2(r2.w), w11, c3); \
        c0 = dot2(f2h2(r3.x), w12, c0); \
        c1 = dot2(f2h2(r3.y), w13, c1); \
        c2 = dot2(f2h2(r3.z), w14, c2); \
        c3 = dot2(f2h2(r3.w), w15, c3); \
        float acc = (c0+c1) + (c2+c3); \
        DPP_ADD(acc, 0xB1); \
        DPP_ADD(acc, 0x4E); \
        float hc = fast_tanh(acc + apv); \
        if (p == 0) h[nxt][j] = (_Float16)hc; \
        else if (p == 1) hcell[((size_t)(tt)*NB + n)*128 + j] = hc; \
        bar_sync(); } while (0)

    for (int t = 1023; t > 0; t -= 2) {
        float apN0 = 0.f, apN1 = 0.f;
        if (t - 2 >= 0) apN0 = apre[((size_t)(t-2)*NB + n)*128 + j];
        BWSTEP(0, 1, apA, t);
        if (t - 3 >= 0) apN1 = apre[((size_t)(t-3)*NB + n)*128 + j];
        BWSTEP(1, 0, apB, t - 1);
        apA = apN0; apB = apN1;
    }
#undef BWSTEP
}

// -------------------------------------------------------------------------
// K3: alpha (r6 verbatim)
// -------------------------------------------------------------------------
__global__ __launch_bounds__(256) void k_alpha(
    const float* __restrict__ hcell, const float* __restrict__ wo,
    const float* __restrict__ bo, float* __restrict__ alpha)
{
    __shared__ float lhc[8][128];
    const int tid = threadIdx.x;
    const size_t base = (size_t)blockIdx.x * 8 * 128;
    ((float4*)&lhc[0][0])[tid] = ((const float4*)(hcell + base))[tid];
    __syncthreads();

    const int j = tid & 127, rh = tid >> 7;
    float acc[4] = {0,0,0,0};
    for (int i = 0; i < 128; i += 4) {
        float w0 = wo[(i+0)*128 + j];
        float w1v = wo[(i+1)*128 + j];
        float w2v = wo[(i+2)*128 + j];
        float w3 = wo[(i+3)*128 + j];
        #pragma unroll
        for (int q = 0; q < 4; ++q) {
            float4 hv = *(const float4*)&lhc[rh*4+q][i];
            acc[q] += hv.x*w0 + hv.y*w1v + hv.z*w2v + hv.w*w3;
        }
    }
    float bias = bo[j];
    #pragma unroll
    for (int q = 0; q < 4; ++q) {
        float b = acc[q] + bias;
        float val = (j < 64) ? b : -softplus_f(b);
        alpha[base + (size_t)(rh*4+q)*128 + j] = val;
    }
}

// -------------------------------------------------------------------------
// K4: forward posterior scan. 1024 threads, 1 batch/block, grid NB.
// r6 structure with ALL shuffles moved to DPP (VALU pipe):
// L1: (hh=tid>>2, pp=tid&3): 8 dot2 + quad-DPP allreduce; pp==0 writes lhid.
// L2: (d2=tid>>4, qq=tid&15): 8 dot2 + row allreduce (xor1,xor2,ror4,ror8);
//     replicated epilogue; qq==0 writes lm; qq<4 store outputs.
// -------------------------------------------------------------------------
#define LHF(x) ((x) + (((x) >> 4) << 3))   // pad 8 f16 per 16-elem chunk

__global__ __launch_bounds__(1024, 1) void k_fwscan(
    const float* __restrict__ alpha, const float* __restrict__ preU,
    const float* __restrict__ dynw1, const float* __restrict__ dynw2,
    const float* __restrict__ dynb2, const float* __restrict__ qraw,
    const float* __restrict__ m0, const float* __restrict__ v0,
    float* __restrict__ out)
{
    const int n = blockIdx.x;
    const int tid = threadIdx.x;
    const int hh = tid >> 2, pp = tid & 3;
    const int d2 = tid >> 4, qq = tid & 15;
    __shared__ _Float16 lm[2][64];
    __shared__ _Float16 lhid[384];

    h2 u0, u1, u2, u3, u4, u5, u6, u7;   // W1[pp*16+2k..+1][hh]
    {
        const float* s = dynw1 + (size_t)(pp * 16) * 256 + hh;
        u0 = h2{(_Float16)s[0*256], (_Float16)s[1*256]};
        u1 = h2{(_Float16)s[2*256], (_Float16)s[3*256]};
        u2 = h2{(_Float16)s[4*256], (_Float16)s[5*256]};
        u3 = h2{(_Float16)s[6*256], (_Float16)s[7*256]};
        u4 = h2{(_Float16)s[8*256], (_Float16)s[9*256]};
        u5 = h2{(_Float16)s[10*256], (_Float16)s[11*256]};
        u6 = h2{(_Float16)s[12*256], (_Float16)s[13*256]};
        u7 = h2{(_Float16)s[14*256], (_Float16)s[15*256]};
    }
    h2 v0p, v1p, v2p, v3p, v4p, v5p, v6p, v7p;  // W2[qq*16+2k..+1][d2]
    {
        const float* s = dynw2 + (size_t)(qq * 16) * 64 + d2;
        v0p = h2{(_Float16)s[0*64], (_Float16)s[1*64]};
        v1p = h2{(_Float16)s[2*64], (_Float16)s[3*64]};
        v2p = h2{(_Float16)s[4*64], (_Float16)s[5*64]};
        v3p = h2{(_Float16)s[6*64], (_Float16)s[7*64]};
        v4p = h2{(_Float16)s[8*64], (_Float16)s[9*64]};
        v5p = h2{(_Float16)s[10*64], (_Float16)s[11*64]};
        v6p = h2{(_Float16)s[12*64], (_Float16)s[13*64]};
        v7p = h2{(_Float16)s[14*64], (_Float16)s[15*64]};
    }

    const float Qv  = softplus_f(qraw[d2]);
    const float b2v = dynb2[d2];
    float vreg = v0[d2];
    if (tid < 64) lm[0][tid] = (_Float16)m0[tid];

    // prefetch ring, distance 2
    float hp0 = preU[(size_t)n * 256 + hh];
    float a10 = alpha[(size_t)n * 128 + d2];
    float a20 = alpha[(size_t)n * 128 + 64 + d2];
    float hp1 = preU[((size_t)NB + n)*256 + hh];
    float a11 = alpha[((size_t)NB + n)*128 + d2];
    float a21 = alpha[((size_t)NB + n)*128 + 64 + d2];
    __syncthreads();

    int cur = 0;
    for (int t = 0; t < T_LEN; ++t) {
        float hpN = 0.f, a1N = 0.f, a2N = 0.f;
        if (t + 2 < T_LEN) {
            hpN = preU[((size_t)(t+2)*NB + n)*256 + hh];
            a1N = alpha[((size_t)(t+2)*NB + n)*128 + d2];
            a2N = alpha[((size_t)(t+2)*NB + n)*128 + 64 + d2];
        }

        // L1: partial dot over m slice (f16), quad-DPP allreduce
        {
            const _Float16* mb = &lm[cur][pp*16];
            float4 r0 = *(const float4*)mb;
            float4 r1 = *(const float4*)(mb + 8);
            float c0 = dot2(f2h2(r0.x), u0, 0.f);
            float c1 = dot2(f2h2(r0.y), u1, 0.f);
            float c2 = dot2(f2h2(r0.z), u2, 0.f);
            float c3 = dot2(f2h2(r0.w), u3, 0.f);
            c0 = dot2(f2h2(r1.x), u4, c0);
            c1 = dot2(f2h2(r1.y), u5, c1);
            c2 = dot2(f2h2(r1.z), u6, c2);
            c3 = dot2(f2h2(r1.w), u7, c3);
            float acc = (c0+c1) + (c2+c3);
            DPP_ADD(acc, 0xB1);
            DPP_ADD(acc, 0x4E);
            if (pp == 0) lhid[LHF(hh)] = (_Float16)fast_tanh(hp0 + acc);
        }
        bar_sync();

        // L2: partial dot over hid slice (f16), 16-lane row allreduce via DPP
        {
            const _Float16* hb = &lhid[LHF(qq*16)];
            float4 r0 = *(const float4*)hb;
            float4 r1 = *(const float4*)(hb + 8);
            float c0 = dot2(f2h2(r0.x), v0p, 0.f);
            float c1 = dot2(f2h2(r0.y), v1p, 0.f);
            float c2 = dot2(f2h2(r0.z), v2p, 0.f);
            float c3 = dot2(f2h2(r0.w), v3p, 0.f);
            c0 = dot2(f2h2(r1.x), v4p, c0);
            c1 = dot2(f2h2(r1.y), v5p, c1);
            c2 = dot2(f2h2(r1.z), v6p, c2);
            c3 = dot2(f2h2(r1.w), v7p, c3);
            float acc = (c0+c1) + (c2+c3);
            DPP_ADD(acc, 0xB1);
            DPP_ADD(acc, 0x4E);
            DPP_ADD(acc, 0x124);   // ROW_ROR:4
            DPP_ADD(acc, 0x128);   // ROW_ROR:8

            float m_p = acc + b2v;
            float v_p = vreg + Qv;
            float rvp = __builtin_amdgcn_rcpf(v_p);
            float e1 = m_p * rvp + a10;
            float e2 = a20 - 0.5f * rvp;
            float v_s = -0.5f * __builtin_amdgcn_rcpf(e2);
            float m_s = v_s * e1;
            vreg = v_s;
            if (qq == 0) lm[cur ^ 1][d2] = (_Float16)m_s;

            if (qq < 4) {
                size_t ob = ((size_t)n * T_LEN + t) * 256;
                float val = (qq == 0) ? m_s : (qq == 1) ? v_s : (qq == 2) ? m_p : v_p;
                out[ob + (size_t)qq*64 + d2] = val;
            }
        }
        bar_sync();
        cur ^= 1;
        hp0 = hp1; a10 = a11; a20 = a21;
        hp1 = hpN; a11 = a1N; a21 = a2N;
    }
}

// -------------------------------------------------------------------------
extern "C" void kernel_launch(void* const* d_in, const int* in_sizes, int n_in,
                              void* d_out, int out_size, void* d_ws, size_t ws_size,
                              hipStream_t stream) {
    const float* y      = (const float*)d_in[1];
    const float* u      = (const float*)d_in[2];
    const float* enc_w1 = (const float*)d_in[3];
    const float* enc_b1 = (const float*)d_in[4];
    const float* enc_w2 = (const float*)d_in[5];
    const float* enc_b2 = (const float*)d_in[6];
    const float* bw_wa  = (const float*)d_in[7];
    const float* bw_wh  = (const float*)d_in[8];
    const float* bw_b   = (const float*)d_in[9];
    const float* bw_wo  = (const float*)d_in[10];
    const float* bw_bo  = (const float*)d_in[11];
    const float* dyn_w1 = (const float*)d_in[12];
    const float* dyn_b1 = (const float*)d_in[13];
    const float* dyn_w2 = (const float*)d_in[14];
    const float* dyn_b2 = (const float*)d_in[15];
    const float* q_raw  = (const float*)d_in[16];
    const float* m0     = (const float*)d_in[17];
    const float* v0     = (const float*)d_in[18];
    float* out = (float*)d_out;

    float* ws = (float*)d_ws;
    float* apre  = ws;                  // [T*NB][128]
    float* hcell = ws + 4194304;        // [T*NB][128]
    float* alpha = ws;                  // aliases apre (apre dead after K2)
    float* preU  = ws + 2 * 4194304;    // [T*NB][256]

    k_encoder<<<4096, 256, 0, stream>>>(y, u, enc_w1, enc_b1, enc_w2, enc_b2,
                                        bw_wa, bw_b, dyn_w1, dyn_b1, apre, preU);
    k_bwscan<<<NB, 512, 0, stream>>>(apre, bw_wh, hcell);
    k_alpha<<<4096, 256, 0, stream>>>(hcell, bw_wo, bw_bo, alpha);
    k_fwscan<<<NB, 1024, 0, stream>>>(alpha, preU, dyn_w1, dyn_w2, dyn_b2,
                                      q_raw, m0, v0, out);
}

// Round 15
// 1245.286 us; speedup vs baseline: 15.2010x; 1.0179x over previous
//
#include <hip/hip_runtime.h>
#include <math.h>

// XFADS: N=32, T=1024, D_OBS=128, D_Z=64, D_U=8, H_ENC=256, H_BW=128, H_DYN=256, D_A=128
#define T_LEN 1024
#define NB 32

typedef _Float16 h2 __attribute__((ext_vector_type(2)));

__device__ __forceinline__ h2 f2h2(float f) { return __builtin_bit_cast(h2, f); }

__device__ __forceinline__ float dot2(h2 a, h2 b, float c) {
#if __has_builtin(__builtin_amdgcn_fdot2)
    return __builtin_amdgcn_fdot2(a, b, c, false);
#else
    return fmaf((float)a[0], (float)b[0], fmaf((float)a[1], (float)b[1], c));
#endif
}

// cross-lane add via DPP (VALU pipe, not DS): ctrl literal.
// 0xB1 = quad xor1 ; 0x4E = quad xor2 ; 0x141 = ROW_HALF_MIRROR (xor7 in 8);
// 0x124 = ROW_ROR:4 ; 0x128 = ROW_ROR:8.
#define DPP_ADD(v, ctrl) do { \
    int _xi = __builtin_bit_cast(int, v); \
    int _yi = __builtin_amdgcn_update_dpp(_xi, _xi, (ctrl), 0xF, 0xF, true); \
    v += __builtin_bit_cast(float, _yi); } while (0)

__device__ __forceinline__ float softplus_f(float x) {
    return fmaxf(x, 0.f) + log1pf(expf(-fabsf(x)));
}

__device__ __forceinline__ float fast_tanh(float x) {
    float e = __builtin_amdgcn_exp2f(x * 2.88539008177792681472f);
    float r = __builtin_amdgcn_rcpf(1.f + e);
    return 1.f - 2.f * r;
}

// raw barrier: drain LDS ops only; global prefetches stay in flight
__device__ __forceinline__ void bar_sync() {
    asm volatile("s_waitcnt lgkmcnt(0)" ::: "memory");
    __builtin_amdgcn_s_barrier();
    asm volatile("" ::: "memory");
}

// -------------------------------------------------------------------------
// K1: encoder (unchanged)
// -------------------------------------------------------------------------
__global__ __launch_bounds__(256) void k_encoder(
    const float* __restrict__ y, const float* __restrict__ u,
    const float* __restrict__ w1, const float* __restrict__ b1,
    const float* __restrict__ w2, const float* __restrict__ b2,
    const float* __restrict__ wa, const float* __restrict__ bb,
    const float* __restrict__ dynw1, const float* __restrict__ dynb1,
    float* __restrict__ apre, float* __restrict__ preU)
{
    __shared__ float ly[8][128];
    __shared__ float lh[8][256];
    __shared__ float la[8][128];
    __shared__ float lu[8][8];
    const int tid = threadIdx.x;
    const int row0 = blockIdx.x * 8;

    ((float4*)&ly[0][0])[tid] = ((const float4*)(y + (size_t)row0 * 128))[tid];
    if (tid < 16)
        ((float4*)&lu[0][0])[tid] = ((const float4*)(u + (size_t)row0 * 8))[tid];
    __syncthreads();

    {
        float acc[8] = {0,0,0,0,0,0,0,0};
        for (int i = 0; i < 128; i += 4) {
            float w0 = w1[(i+0)*256 + tid];
            float w1v = w1[(i+1)*256 + tid];
            float w2v = w1[(i+2)*256 + tid];
            float w3 = w1[(i+3)*256 + tid];
            #pragma unroll
            for (int r = 0; r < 8; ++r) {
                float4 yv = *(const float4*)&ly[r][i];
                acc[r] += yv.x*w0 + yv.y*w1v + yv.z*w2v + yv.w*w3;
            }
        }
        float bias = b1[tid];
        #pragma unroll
        for (int r = 0; r < 8; ++r) lh[r][tid] = fast_tanh(acc[r] + bias);
    }
    __syncthreads();

    {
        const int d = tid & 127, rh = tid >> 7;
        float acc[4] = {0,0,0,0};
        for (int i = 0; i < 256; i += 4) {
            float w0 = w2[(i+0)*128 + d];
            float w1v = w2[(i+1)*128 + d];
            float w2v = w2[(i+2)*128 + d];
            float w3 = w2[(i+3)*128 + d];
            #pragma unroll
            for (int q = 0; q < 4; ++q) {
                float4 hv = *(const float4*)&lh[rh*4+q][i];
                acc[q] += hv.x*w0 + hv.y*w1v + hv.z*w2v + hv.w*w3;
            }
        }
        float bias = b2[d];
        #pragma unroll
        for (int q = 0; q < 4; ++q) la[rh*4+q][d] = acc[q] + bias;
    }
    __syncthreads();

    {
        const int j = tid & 127, rh = tid >> 7;
        float acc[4] = {0,0,0,0};
        for (int i = 0; i < 128; i += 4) {
            float w0 = wa[(i+0)*128 + j];
            float w1v = wa[(i+1)*128 + j];
            float w2v = wa[(i+2)*128 + j];
            float w3 = wa[(i+3)*128 + j];
            #pragma unroll
            for (int q = 0; q < 4; ++q) {
                float4 av = *(const float4*)&la[rh*4+q][i];
                acc[q] += av.x*w0 + av.y*w1v + av.z*w2v + av.w*w3;
            }
        }
        float bias = bb[j];
        #pragma unroll
        for (int q = 0; q < 4; ++q) {
            int rn = row0 + rh*4 + q;
            int n = rn >> 10, t = rn & 1023;
            apre[((size_t)t*NB + n)*128 + j] = acc[q] + bias;
        }
    }

    {
        float wu[8];
        #pragma unroll
        for (int c = 0; c < 8; ++c) wu[c] = dynw1[(64 + c)*256 + tid];
        float bias = dynb1[tid];
        #pragma unroll
        for (int r = 0; r < 8; ++r) {
            float acc = bias;
            #pragma unroll
            for (int c = 0; c < 8; ++c) acc += lu[r][c] * wu[c];
            int rn = row0 + r;
            int n = rn >> 10, t = rn & 1023;
            preU[((size_t)t*NB + n)*256 + tid] = acc;
        }
    }
}

// -------------------------------------------------------------------------
// K2: backward RNN scan. 1024 threads (16 waves, 4/SIMD), 1 batch/block.
// thread (j = tid>>3, p = tid&7): 16-MAC partial (8 dot2) of column j over
// h_f16[p*16..+15]; 8-lane DPP allreduce (xor1, xor2, half-mirror).
// ONE barrier/step; prefetch distance 2 (named ring regs).
// -------------------------------------------------------------------------
__global__ __launch_bounds__(1024, 1) void k_bwscan(
    const float* __restrict__ apre, const float* __restrict__ wh,
    float* __restrict__ hcell)
{
    const int n = blockIdx.x;
    const int tid = threadIdx.x;
    const int j = tid >> 3, p = tid & 7;
    __shared__ _Float16 h[2][128];

    h2 w0, w1, w2, w3, w4, w5, w6, w7;   // Wh[p*16+2k..+1][j]
    {
        const float* s = wh + (size_t)(p * 16) * 128 + j;
        w0 = h2{(_Float16)s[0*128],  (_Float16)s[1*128]};
        w1 = h2{(_Float16)s[2*128],  (_Float16)s[3*128]};
        w2 = h2{(_Float16)s[4*128],  (_Float16)s[5*128]};
        w3 = h2{(_Float16)s[6*128],  (_Float16)s[7*128]};
        w4 = h2{(_Float16)s[8*128],  (_Float16)s[9*128]};
        w5 = h2{(_Float16)s[10*128], (_Float16)s[11*128]};
        w6 = h2{(_Float16)s[12*128], (_Float16)s[13*128]};
        w7 = h2{(_Float16)s[14*128], (_Float16)s[15*128]};
    }

    if (tid < 128) h[0][tid] = (_Float16)0.f;
    __syncthreads();

    float apA = apre[((size_t)1023*NB + n)*128 + j];
    float apB = apre[((size_t)1022*NB + n)*128 + j];

#define BWSTEP(cur, nxt, apv, tt) do { \
        const _Float16* hb = &h[cur][p*16]; \
        float4 r0 = *(const float4*)hb; \
        float4 r1 = *(const float4*)(hb + 8); \
        float c0 = dot2(f2h2(r0.x), w0, 0.f); \
        float c1 = dot2(f2h2(r0.y), w1, 0.f); \
        float c2 = dot2(f2h2(r0.z), w2, 0.f); \
        float c3 = dot2(f2h2(r0.w), w3, 0.f); \
        c0 = dot2(f2h2(r1.x), w4, c0); \
        c1 = dot2(f2h2(r1.y), w5, c1); \
        c2 = dot2(f2h2(r1.z), w6, c2); \
        c3 = dot2(f2h2(r1.w), w7, c3); \
        float acc = (c0+c1) + (c2+c3); \
        DPP_ADD(acc, 0xB1); \
        DPP_ADD(acc, 0x4E); \
        DPP_ADD(acc, 0x141); \
        float hc = fast_tanh(acc + apv); \
        if (p == 0) h[nxt][j] = (_Float16)hc; \
        else if (p == 1) hcell[((size_t)(tt)*NB + n)*128 + j] = hc; \
        bar_sync(); } while (0)

    for (int t = 1023; t > 0; t -= 2) {
        float apN0 = 0.f, apN1 = 0.f;
        if (t - 2 >= 0) apN0 = apre[((size_t)(t-2)*NB + n)*128 + j];
        BWSTEP(0, 1, apA, t);
        if (t - 3 >= 0) apN1 = apre[((size_t)(t-3)*NB + n)*128 + j];
        BWSTEP(1, 0, apB, t - 1);
        apA = apN0; apB = apN1;
    }
#undef BWSTEP
}

// -------------------------------------------------------------------------
// K3: b = hcell @ wo + bo; alpha PACKED as float2 pairs:
// alpha[row*128 + d*2 + 0] = b[d]; alpha[row*128 + d*2 + 1] = -softplus(b[64+d])
// -------------------------------------------------------------------------
__global__ __launch_bounds__(256) void k_alpha(
    const float* __restrict__ hcell, const float* __restrict__ wo,
    const float* __restrict__ bo, float* __restrict__ alpha)
{
    __shared__ float lhc[8][128];
    const int tid = threadIdx.x;
    const size_t base = (size_t)blockIdx.x * 8 * 128;
    ((float4*)&lhc[0][0])[tid] = ((const float4*)(hcell + base))[tid];
    __syncthreads();

    const int j = tid & 127, rh = tid >> 7;
    float acc[4] = {0,0,0,0};
    for (int i = 0; i < 128; i += 4) {
        float w0 = wo[(i+0)*128 + j];
        float w1v = wo[(i+1)*128 + j];
        float w2v = wo[(i+2)*128 + j];
        float w3 = wo[(i+3)*128 + j];
        #pragma unroll
        for (int q = 0; q < 4; ++q) {
            float4 hv = *(const float4*)&lhc[rh*4+q][i];
            acc[q] += hv.x*w0 + hv.y*w1v + hv.z*w2v + hv.w*w3;
        }
    }
    float bias = bo[j];
    const int dpos = (j & 63) * 2 + (j >> 6);   // interleaved pair layout
    #pragma unroll
    for (int q = 0; q < 4; ++q) {
        float b = acc[q] + bias;
        float val = (j < 64) ? b : -softplus_f(b);
        alpha[base + (size_t)(rh*4+q)*128 + dpos] = val;
    }
}

// -------------------------------------------------------------------------
// K4: forward posterior scan. 1024 threads, 1 batch/block.
// L1 (ALL 16 waves): (hh=tid>>2, pp=tid&3): 8 dot2 + quad-DPP; pp==0 writes.
// L2 (waves 0-7 ONLY, tid<512): (d2=tid>>3, qq=tid&7): 16 dot2 + 3 DPP +
//     epilogue (x8 replication); waves 8-15 skip entirely (execz).
// L2's 32-elem hid slice spans TWO padded chunks -> two base pointers
// (LHF(qq*32) and LHF(qq*32+16)) — r14's NaN bug was reading the pad.
// -------------------------------------------------------------------------
#define LHF(x) ((x) + (((x) >> 4) << 3))   // pad 8 f16 per 16-elem chunk

__global__ __launch_bounds__(1024, 1) void k_fwscan(
    const float* __restrict__ alpha, const float* __restrict__ preU,
    const float* __restrict__ dynw1, const float* __restrict__ dynw2,
    const float* __restrict__ dynb2, const float* __restrict__ qraw,
    const float* __restrict__ m0, const float* __restrict__ v0,
    float* __restrict__ out)
{
    const int n = blockIdx.x;
    const int tid = threadIdx.x;
    const int hh = tid >> 2, pp = tid & 3;
    const int d2 = (tid >> 3) & 63, qq = tid & 7;
    const bool lowhalf = (tid < 512);          // wave-uniform
    __shared__ _Float16 lm[2][64];
    __shared__ _Float16 lhid[384];

    h2 u0, u1, u2, u3, u4, u5, u6, u7;   // W1[pp*16+2k..+1][hh]
    {
        const float* s = dynw1 + (size_t)(pp * 16) * 256 + hh;
        u0 = h2{(_Float16)s[0*256], (_Float16)s[1*256]};
        u1 = h2{(_Float16)s[2*256], (_Float16)s[3*256]};
        u2 = h2{(_Float16)s[4*256], (_Float16)s[5*256]};
        u3 = h2{(_Float16)s[6*256], (_Float16)s[7*256]};
        u4 = h2{(_Float16)s[8*256], (_Float16)s[9*256]};
        u5 = h2{(_Float16)s[10*256], (_Float16)s[11*256]};
        u6 = h2{(_Float16)s[12*256], (_Float16)s[13*256]};
        u7 = h2{(_Float16)s[14*256], (_Float16)s[15*256]};
    }
    // W2[qq*32+2k..+1][d2] — 32-deep slice (16 dot2), used by tid<512 only
    h2 v0p, v1p, v2p, v3p, v4p, v5p, v6p, v7p;
    h2 v8p, v9p, vap, vbp, vcp, vdp, vep, vfp;
    {
        const float* s = dynw2 + (size_t)(qq * 32) * 64 + d2;
        v0p = h2{(_Float16)s[0*64],  (_Float16)s[1*64]};
        v1p = h2{(_Float16)s[2*64],  (_Float16)s[3*64]};
        v2p = h2{(_Float16)s[4*64],  (_Float16)s[5*64]};
        v3p = h2{(_Float16)s[6*64],  (_Float16)s[7*64]};
        v4p = h2{(_Float16)s[8*64],  (_Float16)s[9*64]};
        v5p = h2{(_Float16)s[10*64], (_Float16)s[11*64]};
        v6p = h2{(_Float16)s[12*64], (_Float16)s[13*64]};
        v7p = h2{(_Float16)s[14*64], (_Float16)s[15*64]};
        v8p = h2{(_Float16)s[16*64], (_Float16)s[17*64]};
        v9p = h2{(_Float16)s[18*64], (_Float16)s[19*64]};
        vap = h2{(_Float16)s[20*64], (_Float16)s[21*64]};
        vbp = h2{(_Float16)s[22*64], (_Float16)s[23*64]};
        vcp = h2{(_Float16)s[24*64], (_Float16)s[25*64]};
        vdp = h2{(_Float16)s[26*64], (_Float16)s[27*64]};
        vep = h2{(_Float16)s[28*64], (_Float16)s[29*64]};
        vfp = h2{(_Float16)s[30*64], (_Float16)s[31*64]};
    }

    const float Qv  = softplus_f(qraw[d2]);
    const float b2v = dynb2[d2];
    float vreg = v0[d2];
    if (tid < 64) lm[0][tid] = (_Float16)m0[tid];

    // prefetch ring, distance 2
    float hp0 = preU[(size_t)n * 256 + hh];
    float hp1 = preU[((size_t)NB + n)*256 + hh];
    float2 av0 = make_float2(0.f, 0.f), av1 = make_float2(0.f, 0.f);
    if (lowhalf) {
        av0 = *(const float2*)&alpha[(size_t)n * 128 + d2*2];
        av1 = *(const float2*)&alpha[((size_t)NB + n)*128 + d2*2];
    }
    __syncthreads();

    int cur = 0;
    for (int t = 0; t < T_LEN; ++t) {
        float hpN = 0.f;
        float2 avN = make_float2(0.f, 0.f);
        if (t + 2 < T_LEN) {
            hpN = preU[((size_t)(t+2)*NB + n)*256 + hh];
            if (lowhalf)
                avN = *(const float2*)&alpha[((size_t)(t+2)*NB + n)*128 + d2*2];
        }

        // L1: all waves — partial dot over m slice, quad-DPP allreduce
        {
            const _Float16* mb = &lm[cur][pp*16];
            float4 r0 = *(const float4*)mb;
            float4 r1 = *(const float4*)(mb + 8);
            float c0 = dot2(f2h2(r0.x), u0, 0.f);
            float c1 = dot2(f2h2(r0.y), u1, 0.f);
            float c2 = dot2(f2h2(r0.z), u2, 0.f);
            float c3 = dot2(f2h2(r0.w), u3, 0.f);
            c0 = dot2(f2h2(r1.x), u4, c0);
            c1 = dot2(f2h2(r1.y), u5, c1);
            c2 = dot2(f2h2(r1.z), u6, c2);
            c3 = dot2(f2h2(r1.w), u7, c3);
            float acc = (c0+c1) + (c2+c3);
            DPP_ADD(acc, 0xB1);
            DPP_ADD(acc, 0x4E);
            if (pp == 0) lhid[LHF(hh)] = (_Float16)fast_tanh(hp0 + acc);
        }
        bar_sync();

        // L2: waves 0-7 only — 32-deep partial + 8-lane DPP + epilogue
        if (lowhalf) {
            const _Float16* hbA = &lhid[LHF(qq*32)];        // elems 0..15
            const _Float16* hbB = &lhid[LHF(qq*32 + 16)];   // elems 16..31
            float4 r0 = *(const float4*)hbA;
            float4 r1 = *(const float4*)(hbA + 8);
            float4 r2 = *(const float4*)hbB;
            float4 r3 = *(const float4*)(hbB + 8);
            float c0 = dot2(f2h2(r0.x), v0p, 0.f);
            float c1 = dot2(f2h2(r0.y), v1p, 0.f);
            float c2 = dot2(f2h2(r0.z), v2p, 0.f);
            float c3 = dot2(f2h2(r0.w), v3p, 0.f);
            c0 = dot2(f2h2(r1.x), v4p, c0);
            c1 = dot2(f2h2(r1.y), v5p, c1);
            c2 = dot2(f2h2(r1.z), v6p, c2);
            c3 = dot2(f2h2(r1.w), v7p, c3);
            c0 = dot2(f2h2(r2.x), v8p, c0);
            c1 = dot2(f2h2(r2.y), v9p, c1);
            c2 = dot2(f2h2(r2.z), vap, c2);
            c3 = dot2(f2h2(r2.w), vbp, c3);
            c0 = dot2(f2h2(r3.x), vcp, c0);
            c1 = dot2(f2h2(r3.y), vdp, c1);
            c2 = dot2(f2h2(r3.z), vep, c2);
            c3 = dot2(f2h2(r3.w), vfp, c3);
            float acc = (c0+c1) + (c2+c3);
            DPP_ADD(acc, 0xB1);
            DPP_ADD(acc, 0x4E);
            DPP_ADD(acc, 0x141);

            float m_p = acc + b2v;
            float v_p = vreg + Qv;
            float rvp = __builtin_amdgcn_rcpf(v_p);
            float e1 = m_p * rvp + av0.x;
            float e2 = av0.y - 0.5f * rvp;
            float v_s = -0.5f * __builtin_amdgcn_rcpf(e2);
            float m_s = v_s * e1;
            vreg = v_s;
            if (qq == 0) lm[cur ^ 1][d2] = (_Float16)m_s;

            if (qq < 4) {
                size_t ob = ((size_t)n * T_LEN + t) * 256;
                float val = (qq == 0) ? m_s : (qq == 1) ? v_s : (qq == 2) ? m_p : v_p;
                out[ob + (size_t)qq*64 + d2] = val;
            }
        }
        bar_sync();
        cur ^= 1;
        hp0 = hp1; hp1 = hpN;
        av0 = av1; av1 = avN;
    }
}

// -------------------------------------------------------------------------
extern "C" void kernel_launch(void* const* d_in, const int* in_sizes, int n_in,
                              void* d_out, int out_size, void* d_ws, size_t ws_size,
                              hipStream_t stream) {
    const float* y      = (const float*)d_in[1];
    const float* u      = (const float*)d_in[2];
    const float* enc_w1 = (const float*)d_in[3];
    const float* enc_b1 = (const float*)d_in[4];
    const float* enc_w2 = (const float*)d_in[5];
    const float* enc_b2 = (const float*)d_in[6];
    const float* bw_wa  = (const float*)d_in[7];
    const float* bw_wh  = (const float*)d_in[8];
    const float* bw_b   = (const float*)d_in[9];
    const float* bw_wo  = (const float*)d_in[10];
    const float* bw_bo  = (const float*)d_in[11];
    const float* dyn_w1 = (const float*)d_in[12];
    const float* dyn_b1 = (const float*)d_in[13];
    const float* dyn_w2 = (const float*)d_in[14];
    const float* dyn_b2 = (const float*)d_in[15];
    const float* q_raw  = (const float*)d_in[16];
    const float* m0     = (const float*)d_in[17];
    const float* v0     = (const float*)d_in[18];
    float* out = (float*)d_out;

    float* ws = (float*)d_ws;
    float* apre  = ws;                  // [T*NB][128]
    float* hcell = ws + 4194304;        // [T*NB][128]
    float* alpha = ws;                  // aliases apre (packed float2 pairs)
    float* preU  = ws + 2 * 4194304;    // [T*NB][256]

    k_encoder<<<4096, 256, 0, stream>>>(y, u, enc_w1, enc_b1, enc_w2, enc_b2,
                                        bw_wa, bw_b, dyn_w1, dyn_b1, apre, preU);
    k_bwscan<<<NB, 1024, 0, stream>>>(apre, bw_wh, hcell);
    k_alpha<<<4096, 256, 0, stream>>>(hcell, bw_wo, bw_bo, alpha);
    k_fwscan<<<NB, 1024, 0, stream>>>(alpha, preU, dyn_w1, dyn_w2, dyn_b2,
                                      q_raw, m0, v0, out);
}

// Round 16
// 1143.280 us; speedup vs baseline: 16.5572x; 1.0892x over previous
//
#include <hip/hip_runtime.h>
#include <math.h>

// XFADS: N=32, T=1024, D_OBS=128, D_Z=64, D_U=8, H_ENC=256, H_BW=128, H_DYN=256, D_A=128
#define T_LEN 1024
#define NB 32

typedef _Float16 h2 __attribute__((ext_vector_type(2)));

__device__ __forceinline__ h2 f2h2(float f) { return __builtin_bit_cast(h2, f); }

__device__ __forceinline__ float dot2(h2 a, h2 b, float c) {
#if __has_builtin(__builtin_amdgcn_fdot2)
    return __builtin_amdgcn_fdot2(a, b, c, false);
#else
    return fmaf((float)a[0], (float)b[0], fmaf((float)a[1], (float)b[1], c));
#endif
}

// cross-lane add via DPP (VALU pipe): 0xB1 = quad xor1 ; 0x4E = quad xor2 ;
// 0x141 = ROW_HALF_MIRROR (xor7 within 8).
#define DPP_ADD(v, ctrl) do { \
    int _xi = __builtin_bit_cast(int, v); \
    int _yi = __builtin_amdgcn_update_dpp(_xi, _xi, (ctrl), 0xF, 0xF, true); \
    v += __builtin_bit_cast(float, _yi); } while (0)

__device__ __forceinline__ float softplus_f(float x) {
    return fmaxf(x, 0.f) + log1pf(expf(-fabsf(x)));
}

__device__ __forceinline__ float fast_tanh(float x) {
    float e = __builtin_amdgcn_exp2f(x * 2.88539008177792681472f);
    float r = __builtin_amdgcn_rcpf(1.f + e);
    return 1.f - 2.f * r;
}

// raw barrier: drain LDS ops only; global prefetches stay in flight
__device__ __forceinline__ void bar_sync() {
    asm volatile("s_waitcnt lgkmcnt(0)" ::: "memory");
    __builtin_amdgcn_s_barrier();
    asm volatile("" ::: "memory");
}

// -------------------------------------------------------------------------
// K1: encoder (unchanged)
// -------------------------------------------------------------------------
__global__ __launch_bounds__(256) void k_encoder(
    const float* __restrict__ y, const float* __restrict__ u,
    const float* __restrict__ w1, const float* __restrict__ b1,
    const float* __restrict__ w2, const float* __restrict__ b2,
    const float* __restrict__ wa, const float* __restrict__ bb,
    const float* __restrict__ dynw1, const float* __restrict__ dynb1,
    float* __restrict__ apre, float* __restrict__ preU)
{
    __shared__ float ly[8][128];
    __shared__ float lh[8][256];
    __shared__ float la[8][128];
    __shared__ float lu[8][8];
    const int tid = threadIdx.x;
    const int row0 = blockIdx.x * 8;

    ((float4*)&ly[0][0])[tid] = ((const float4*)(y + (size_t)row0 * 128))[tid];
    if (tid < 16)
        ((float4*)&lu[0][0])[tid] = ((const float4*)(u + (size_t)row0 * 8))[tid];
    __syncthreads();

    {
        float acc[8] = {0,0,0,0,0,0,0,0};
        for (int i = 0; i < 128; i += 4) {
            float w0 = w1[(i+0)*256 + tid];
            float w1v = w1[(i+1)*256 + tid];
            float w2v = w1[(i+2)*256 + tid];
            float w3 = w1[(i+3)*256 + tid];
            #pragma unroll
            for (int r = 0; r < 8; ++r) {
                float4 yv = *(const float4*)&ly[r][i];
                acc[r] += yv.x*w0 + yv.y*w1v + yv.z*w2v + yv.w*w3;
            }
        }
        float bias = b1[tid];
        #pragma unroll
        for (int r = 0; r < 8; ++r) lh[r][tid] = fast_tanh(acc[r] + bias);
    }
    __syncthreads();

    {
        const int d = tid & 127, rh = tid >> 7;
        float acc[4] = {0,0,0,0};
        for (int i = 0; i < 256; i += 4) {
            float w0 = w2[(i+0)*128 + d];
            float w1v = w2[(i+1)*128 + d];
            float w2v = w2[(i+2)*128 + d];
            float w3 = w2[(i+3)*128 + d];
            #pragma unroll
            for (int q = 0; q < 4; ++q) {
                float4 hv = *(const float4*)&lh[rh*4+q][i];
                acc[q] += hv.x*w0 + hv.y*w1v + hv.z*w2v + hv.w*w3;
            }
        }
        float bias = b2[d];
        #pragma unroll
        for (int q = 0; q < 4; ++q) la[rh*4+q][d] = acc[q] + bias;
    }
    __syncthreads();

    {
        const int j = tid & 127, rh = tid >> 7;
        float acc[4] = {0,0,0,0};
        for (int i = 0; i < 128; i += 4) {
            float w0 = wa[(i+0)*128 + j];
            float w1v = wa[(i+1)*128 + j];
            float w2v = wa[(i+2)*128 + j];
            float w3 = wa[(i+3)*128 + j];
            #pragma unroll
            for (int q = 0; q < 4; ++q) {
                float4 av = *(const float4*)&la[rh*4+q][i];
                acc[q] += av.x*w0 + av.y*w1v + av.z*w2v + av.w*w3;
            }
        }
        float bias = bb[j];
        #pragma unroll
        for (int q = 0; q < 4; ++q) {
            int rn = row0 + rh*4 + q;
            int n = rn >> 10, t = rn & 1023;
            apre[((size_t)t*NB + n)*128 + j] = acc[q] + bias;
        }
    }

    {
        float wu[8];
        #pragma unroll
        for (int c = 0; c < 8; ++c) wu[c] = dynw1[(64 + c)*256 + tid];
        float bias = dynb1[tid];
        #pragma unroll
        for (int r = 0; r < 8; ++r) {
            float acc = bias;
            #pragma unroll
            for (int c = 0; c < 8; ++c) acc += lu[r][c] * wu[c];
            int rn = row0 + r;
            int n = rn >> 10, t = rn & 1023;
            preU[((size_t)t*NB + n)*256 + tid] = acc;
        }
    }
}

// -------------------------------------------------------------------------
// K2: backward RNN scan — r13's measured-best 512-thread form.
// thread (j = tid>>2, p = tid&3): 32-MAC partial (16 dot2) of column j over
// h_f16[p*32..+31]; quad-DPP allreduce (xor1+xor2). ONE barrier/step.
// -------------------------------------------------------------------------
__global__ __launch_bounds__(512, 1) void k_bwscan(
    const float* __restrict__ apre, const float* __restrict__ wh,
    float* __restrict__ hcell)
{
    const int n = blockIdx.x;
    const int tid = threadIdx.x;
    const int j = tid >> 2, p = tid & 3;
    __shared__ _Float16 h[2][128];

    h2 w0, w1, w2, w3, w4, w5, w6, w7, w8, w9, w10, w11, w12, w13, w14, w15;
    {
        const float* s = wh + (size_t)(p * 32) * 128 + j;
        w0  = h2{(_Float16)s[0*128],  (_Float16)s[1*128]};
        w1  = h2{(_Float16)s[2*128],  (_Float16)s[3*128]};
        w2  = h2{(_Float16)s[4*128],  (_Float16)s[5*128]};
        w3  = h2{(_Float16)s[6*128],  (_Float16)s[7*128]};
        w4  = h2{(_Float16)s[8*128],  (_Float16)s[9*128]};
        w5  = h2{(_Float16)s[10*128], (_Float16)s[11*128]};
        w6  = h2{(_Float16)s[12*128], (_Float16)s[13*128]};
        w7  = h2{(_Float16)s[14*128], (_Float16)s[15*128]};
        w8  = h2{(_Float16)s[16*128], (_Float16)s[17*128]};
        w9  = h2{(_Float16)s[18*128], (_Float16)s[19*128]};
        w10 = h2{(_Float16)s[20*128], (_Float16)s[21*128]};
        w11 = h2{(_Float16)s[22*128], (_Float16)s[23*128]};
        w12 = h2{(_Float16)s[24*128], (_Float16)s[25*128]};
        w13 = h2{(_Float16)s[26*128], (_Float16)s[27*128]};
        w14 = h2{(_Float16)s[28*128], (_Float16)s[29*128]};
        w15 = h2{(_Float16)s[30*128], (_Float16)s[31*128]};
    }

    if (tid < 128) h[0][tid] = (_Float16)0.f;
    __syncthreads();

    float apA = apre[((size_t)1023*NB + n)*128 + j];
    float apB = apre[((size_t)1022*NB + n)*128 + j];

#define BWSTEP(cur, nxt, apv, tt) do { \
        const _Float16* hb = &h[cur][p*32]; \
        float4 r0 = *(const float4*)hb; \
        float4 r1 = *(const float4*)(hb + 8); \
        float4 r2 = *(const float4*)(hb + 16); \
        float4 r3 = *(const float4*)(hb + 24); \
        float c0 = dot2(f2h2(r0.x), w0, 0.f); \
        float c1 = dot2(f2h2(r0.y), w1, 0.f); \
        float c2 = dot2(f2h2(r0.z), w2, 0.f); \
        float c3 = dot2(f2h2(r0.w), w3, 0.f); \
        c0 = dot2(f2h2(r1.x), w4, c0); \
        c1 = dot2(f2h2(r1.y), w5, c1); \
        c2 = dot2(f2h2(r1.z), w6, c2); \
        c3 = dot2(f2h2(r1.w), w7, c3); \
        c0 = dot2(f2h2(r2.x), w8, c0); \
        c1 = dot2(f2h2(r2.y), w9, c1); \
        c2 = dot2(f2h2(r2.z), w10, c2); \
        c3 = dot2(f2h2(r2.w), w11, c3); \
        c0 = dot2(f2h2(r3.x), w12, c0); \
        c1 = dot2(f2h2(r3.y), w13, c1); \
        c2 = dot2(f2h2(r3.z), w14, c2); \
        c3 = dot2(f2h2(r3.w), w15, c3); \
        float acc = (c0+c1) + (c2+c3); \
        DPP_ADD(acc, 0xB1); \
        DPP_ADD(acc, 0x4E); \
        float hc = fast_tanh(acc + apv); \
        if (p == 0) h[nxt][j] = (_Float16)hc; \
        else if (p == 1) hcell[((size_t)(tt)*NB + n)*128 + j] = hc; \
        bar_sync(); } while (0)

    for (int t = 1023; t > 0; t -= 2) {
        float apN0 = 0.f, apN1 = 0.f;
        if (t - 2 >= 0) apN0 = apre[((size_t)(t-2)*NB + n)*128 + j];
        BWSTEP(0, 1, apA, t);
        if (t - 3 >= 0) apN1 = apre[((size_t)(t-3)*NB + n)*128 + j];
        BWSTEP(1, 0, apB, t - 1);
        apA = apN0; apB = apN1;
    }
#undef BWSTEP
}

// -------------------------------------------------------------------------
// K3: b = hcell @ wo + bo; alpha PACKED as float2 pairs (unchanged)
// -------------------------------------------------------------------------
__global__ __launch_bounds__(256) void k_alpha(
    const float* __restrict__ hcell, const float* __restrict__ wo,
    const float* __restrict__ bo, float* __restrict__ alpha)
{
    __shared__ float lhc[8][128];
    const int tid = threadIdx.x;
    const size_t base = (size_t)blockIdx.x * 8 * 128;
    ((float4*)&lhc[0][0])[tid] = ((const float4*)(hcell + base))[tid];
    __syncthreads();

    const int j = tid & 127, rh = tid >> 7;
    float acc[4] = {0,0,0,0};
    for (int i = 0; i < 128; i += 4) {
        float w0 = wo[(i+0)*128 + j];
        float w1v = wo[(i+1)*128 + j];
        float w2v = wo[(i+2)*128 + j];
        float w3 = wo[(i+3)*128 + j];
        #pragma unroll
        for (int q = 0; q < 4; ++q) {
            float4 hv = *(const float4*)&lhc[rh*4+q][i];
            acc[q] += hv.x*w0 + hv.y*w1v + hv.z*w2v + hv.w*w3;
        }
    }
    float bias = bo[j];
    const int dpos = (j & 63) * 2 + (j >> 6);   // interleaved pair layout
    #pragma unroll
    for (int q = 0; q < 4; ++q) {
        float b = acc[q] + bias;
        float val = (j < 64) ? b : -softplus_f(b);
        alpha[base + (size_t)(rh*4+q)*128 + dpos] = val;
    }
}

// -------------------------------------------------------------------------
// K4: forward posterior scan. 512 threads (8 waves, 2/SIMD), 1 batch/block.
// L1: (hh = tid>>1, pp = tid&1): 32-deep slice (16 dot2) + ONE DPP (xor1);
//     pp==0 writes lhid (padded per 16, two chunk-correct pointers).
// L2: all 8 waves: (d2 = tid>>3, qq = tid&7): 32-deep slice (16 dot2) +
//     3 DPP (xor1, xor2, half-mirror); epilogue x8 replication.
// 2 barriers/step; alpha as packed float2; named ring registers.
// -------------------------------------------------------------------------
#define LHF(x) ((x) + (((x) >> 4) << 3))   // pad 8 f16 per 16-elem chunk

__global__ __launch_bounds__(512, 1) void k_fwscan(
    const float* __restrict__ alpha, const float* __restrict__ preU,
    const float* __restrict__ dynw1, const float* __restrict__ dynw2,
    const float* __restrict__ dynb2, const float* __restrict__ qraw,
    const float* __restrict__ m0, const float* __restrict__ v0,
    float* __restrict__ out)
{
    const int n = blockIdx.x;
    const int tid = threadIdx.x;
    const int hh = tid >> 1, pp = tid & 1;
    const int d2 = tid >> 3, qq = tid & 7;
    __shared__ _Float16 lm[2][64];
    __shared__ _Float16 lhid[384];

    // W1[pp*32+2k..+1][hh], k=0..15
    h2 u0, u1, u2, u3, u4, u5, u6, u7, u8, u9, ua, ub, uc, ud, ue, uf;
    {
        const float* s = dynw1 + (size_t)(pp * 32) * 256 + hh;
        u0 = h2{(_Float16)s[0*256],  (_Float16)s[1*256]};
        u1 = h2{(_Float16)s[2*256],  (_Float16)s[3*256]};
        u2 = h2{(_Float16)s[4*256],  (_Float16)s[5*256]};
        u3 = h2{(_Float16)s[6*256],  (_Float16)s[7*256]};
        u4 = h2{(_Float16)s[8*256],  (_Float16)s[9*256]};
        u5 = h2{(_Float16)s[10*256], (_Float16)s[11*256]};
        u6 = h2{(_Float16)s[12*256], (_Float16)s[13*256]};
        u7 = h2{(_Float16)s[14*256], (_Float16)s[15*256]};
        u8 = h2{(_Float16)s[16*256], (_Float16)s[17*256]};
        u9 = h2{(_Float16)s[18*256], (_Float16)s[19*256]};
        ua = h2{(_Float16)s[20*256], (_Float16)s[21*256]};
        ub = h2{(_Float16)s[22*256], (_Float16)s[23*256]};
        uc = h2{(_Float16)s[24*256], (_Float16)s[25*256]};
        ud = h2{(_Float16)s[26*256], (_Float16)s[27*256]};
        ue = h2{(_Float16)s[28*256], (_Float16)s[29*256]};
        uf = h2{(_Float16)s[30*256], (_Float16)s[31*256]};
    }
    // W2[qq*32+2k..+1][d2], k=0..15
    h2 v0p, v1p, v2p, v3p, v4p, v5p, v6p, v7p;
    h2 v8p, v9p, vap, vbp, vcp, vdp, vep, vfp;
    {
        const float* s = dynw2 + (size_t)(qq * 32) * 64 + d2;
        v0p = h2{(_Float16)s[0*64],  (_Float16)s[1*64]};
        v1p = h2{(_Float16)s[2*64],  (_Float16)s[3*64]};
        v2p = h2{(_Float16)s[4*64],  (_Float16)s[5*64]};
        v3p = h2{(_Float16)s[6*64],  (_Float16)s[7*64]};
        v4p = h2{(_Float16)s[8*64],  (_Float16)s[9*64]};
        v5p = h2{(_Float16)s[10*64], (_Float16)s[11*64]};
        v6p = h2{(_Float16)s[12*64], (_Float16)s[13*64]};
        v7p = h2{(_Float16)s[14*64], (_Float16)s[15*64]};
        v8p = h2{(_Float16)s[16*64], (_Float16)s[17*64]};
        v9p = h2{(_Float16)s[18*64], (_Float16)s[19*64]};
        vap = h2{(_Float16)s[20*64], (_Float16)s[21*64]};
        vbp = h2{(_Float16)s[22*64], (_Float16)s[23*64]};
        vcp = h2{(_Float16)s[24*64], (_Float16)s[25*64]};
        vdp = h2{(_Float16)s[26*64], (_Float16)s[27*64]};
        vep = h2{(_Float16)s[28*64], (_Float16)s[29*64]};
        vfp = h2{(_Float16)s[30*64], (_Float16)s[31*64]};
    }

    const float Qv  = softplus_f(qraw[d2]);
    const float b2v = dynb2[d2];
    float vreg = v0[d2];
    if (tid < 64) lm[0][tid] = (_Float16)m0[tid];

    // prefetch ring, distance 2
    float hp0 = preU[(size_t)n * 256 + hh];
    float hp1 = preU[((size_t)NB + n)*256 + hh];
    float2 av0 = *(const float2*)&alpha[(size_t)n * 128 + d2*2];
    float2 av1 = *(const float2*)&alpha[((size_t)NB + n)*128 + d2*2];
    __syncthreads();

    int cur = 0;
    for (int t = 0; t < T_LEN; ++t) {
        float hpN = 0.f;
        float2 avN = make_float2(0.f, 0.f);
        if (t + 2 < T_LEN) {
            hpN = preU[((size_t)(t+2)*NB + n)*256 + hh];
            avN = *(const float2*)&alpha[((size_t)(t+2)*NB + n)*128 + d2*2];
        }

        // L1: 32-deep partial over m (broadcast reads), ONE DPP pair-reduce
        {
            const _Float16* mb = &lm[cur][pp*32];
            float4 r0 = *(const float4*)mb;
            float4 r1 = *(const float4*)(mb + 8);
            float4 r2 = *(const float4*)(mb + 16);
            float4 r3 = *(const float4*)(mb + 24);
            float c0 = dot2(f2h2(r0.x), u0, 0.f);
            float c1 = dot2(f2h2(r0.y), u1, 0.f);
            float c2 = dot2(f2h2(r0.z), u2, 0.f);
            float c3 = dot2(f2h2(r0.w), u3, 0.f);
            c0 = dot2(f2h2(r1.x), u4, c0);
            c1 = dot2(f2h2(r1.y), u5, c1);
            c2 = dot2(f2h2(r1.z), u6, c2);
            c3 = dot2(f2h2(r1.w), u7, c3);
            c0 = dot2(f2h2(r2.x), u8, c0);
            c1 = dot2(f2h2(r2.y), u9, c1);
            c2 = dot2(f2h2(r2.z), ua, c2);
            c3 = dot2(f2h2(r2.w), ub, c3);
            c0 = dot2(f2h2(r3.x), uc, c0);
            c1 = dot2(f2h2(r3.y), ud, c1);
            c2 = dot2(f2h2(r3.z), ue, c2);
            c3 = dot2(f2h2(r3.w), uf, c3);
            float acc = (c0+c1) + (c2+c3);
            DPP_ADD(acc, 0xB1);   // pair (pp=0/1) sum
            if (pp == 0) lhid[LHF(hh)] = (_Float16)fast_tanh(hp0 + acc);
        }
        bar_sync();

        // L2: all waves — 32-deep partial + 8-lane DPP allreduce + epilogue
        {
            const _Float16* hbA = &lhid[LHF(qq*32)];        // elems 0..15
            const _Float16* hbB = &lhid[LHF(qq*32 + 16)];   // elems 16..31
            float4 r0 = *(const float4*)hbA;
            float4 r1 = *(const float4*)(hbA + 8);
            float4 r2 = *(const float4*)hbB;
            float4 r3 = *(const float4*)(hbB + 8);
            float c0 = dot2(f2h2(r0.x), v0p, 0.f);
            float c1 = dot2(f2h2(r0.y), v1p, 0.f);
            float c2 = dot2(f2h2(r0.z), v2p, 0.f);
            float c3 = dot2(f2h2(r0.w), v3p, 0.f);
            c0 = dot2(f2h2(r1.x), v4p, c0);
            c1 = dot2(f2h2(r1.y), v5p, c1);
            c2 = dot2(f2h2(r1.z), v6p, c2);
            c3 = dot2(f2h2(r1.w), v7p, c3);
            c0 = dot2(f2h2(r2.x), v8p, c0);
            c1 = dot2(f2h2(r2.y), v9p, c1);
            c2 = dot2(f2h2(r2.z), vap, c2);
            c3 = dot2(f2h2(r2.w), vbp, c3);
            c0 = dot2(f2h2(r3.x), vcp, c0);
            c1 = dot2(f2h2(r3.y), vdp, c1);
            c2 = dot2(f2h2(r3.z), vep, c2);
            c3 = dot2(f2h2(r3.w), vfp, c3);
            float acc = (c0+c1) + (c2+c3);
            DPP_ADD(acc, 0xB1);
            DPP_ADD(acc, 0x4E);
            DPP_ADD(acc, 0x141);

            float m_p = acc + b2v;
            float v_p = vreg + Qv;
            float rvp = __builtin_amdgcn_rcpf(v_p);
            float e1 = m_p * rvp + av0.x;
            float e2 = av0.y - 0.5f * rvp;
            float v_s = -0.5f * __builtin_amdgcn_rcpf(e2);
            float m_s = v_s * e1;
            vreg = v_s;
            if (qq == 0) lm[cur ^ 1][d2] = (_Float16)m_s;

            if (qq < 4) {
                size_t ob = ((size_t)n * T_LEN + t) * 256;
                float val = (qq == 0) ? m_s : (qq == 1) ? v_s : (qq == 2) ? m_p : v_p;
                out[ob + (size_t)qq*64 + d2] = val;
            }
        }
        bar_sync();
        cur ^= 1;
        hp0 = hp1; hp1 = hpN;
        av0 = av1; av1 = avN;
    }
}

// -------------------------------------------------------------------------
extern "C" void kernel_launch(void* const* d_in, const int* in_sizes, int n_in,
                              void* d_out, int out_size, void* d_ws, size_t ws_size,
                              hipStream_t stream) {
    const float* y      = (const float*)d_in[1];
    const float* u      = (const float*)d_in[2];
    const float* enc_w1 = (const float*)d_in[3];
    const float* enc_b1 = (const float*)d_in[4];
    const float* enc_w2 = (const float*)d_in[5];
    const float* enc_b2 = (const float*)d_in[6];
    const float* bw_wa  = (const float*)d_in[7];
    const float* bw_wh  = (const float*)d_in[8];
    const float* bw_b   = (const float*)d_in[9];
    const float* bw_wo  = (const float*)d_in[10];
    const float* bw_bo  = (const float*)d_in[11];
    const float* dyn_w1 = (const float*)d_in[12];
    const float* dyn_b1 = (const float*)d_in[13];
    const float* dyn_w2 = (const float*)d_in[14];
    const float* dyn_b2 = (const float*)d_in[15];
    const float* q_raw  = (const float*)d_in[16];
    const float* m0     = (const float*)d_in[17];
    const float* v0     = (const float*)d_in[18];
    float* out = (float*)d_out;

    float* ws = (float*)d_ws;
    float* apre  = ws;                  // [T*NB][128]
    float* hcell = ws + 4194304;        // [T*NB][128]
    float* alpha = ws;                  // aliases apre (packed float2 pairs)
    float* preU  = ws + 2 * 4194304;    // [T*NB][256]

    k_encoder<<<4096, 256, 0, stream>>>(y, u, enc_w1, enc_b1, enc_w2, enc_b2,
                                        bw_wa, bw_b, dyn_w1, dyn_b1, apre, preU);
    k_bwscan<<<NB, 512, 0, stream>>>(apre, bw_wh, hcell);
    k_alpha<<<4096, 256, 0, stream>>>(hcell, bw_wo, bw_bo, alpha);
    k_fwscan<<<NB, 512, 0, stream>>>(alpha, preU, dyn_w1, dyn_w2, dyn_b2,
                                     q_raw, m0, v0, out);
}

// Round 17
// 1115.127 us; speedup vs baseline: 16.9752x; 1.0252x over previous
//
#include <hip/hip_runtime.h>
#include <math.h>

// XFADS: N=32, T=1024, D_OBS=128, D_Z=64, D_U=8, H_ENC=256, H_BW=128, H_DYN=256, D_A=128
#define T_LEN 1024
#define NB 32

typedef _Float16 h2 __attribute__((ext_vector_type(2)));

__device__ __forceinline__ h2 f2h2(float f) { return __builtin_bit_cast(h2, f); }

__device__ __forceinline__ float dot2(h2 a, h2 b, float c) {
#if __has_builtin(__builtin_amdgcn_fdot2)
    return __builtin_amdgcn_fdot2(a, b, c, false);
#else
    return fmaf((float)a[0], (float)b[0], fmaf((float)a[1], (float)b[1], c));
#endif
}

// cross-lane add via DPP (VALU pipe): 0xB1 = quad xor1 ; 0x4E = quad xor2.
#define DPP_ADD(v, ctrl) do { \
    int _xi = __builtin_bit_cast(int, v); \
    int _yi = __builtin_amdgcn_update_dpp(_xi, _xi, (ctrl), 0xF, 0xF, true); \
    v += __builtin_bit_cast(float, _yi); } while (0)

__device__ __forceinline__ float softplus_f(float x) {
    return fmaxf(x, 0.f) + log1pf(expf(-fabsf(x)));
}

__device__ __forceinline__ float fast_tanh(float x) {
    float e = __builtin_amdgcn_exp2f(x * 2.88539008177792681472f);
    float r = __builtin_amdgcn_rcpf(1.f + e);
    return 1.f - 2.f * r;
}

// raw barrier: drain LDS ops only; global prefetches stay in flight
__device__ __forceinline__ void bar_sync() {
    asm volatile("s_waitcnt lgkmcnt(0)" ::: "memory");
    __builtin_amdgcn_s_barrier();
    asm volatile("" ::: "memory");
}

// -------------------------------------------------------------------------
// K1: encoder (unchanged)
// -------------------------------------------------------------------------
__global__ __launch_bounds__(256) void k_encoder(
    const float* __restrict__ y, const float* __restrict__ u,
    const float* __restrict__ w1, const float* __restrict__ b1,
    const float* __restrict__ w2, const float* __restrict__ b2,
    const float* __restrict__ wa, const float* __restrict__ bb,
    const float* __restrict__ dynw1, const float* __restrict__ dynb1,
    float* __restrict__ apre, float* __restrict__ preU)
{
    __shared__ float ly[8][128];
    __shared__ float lh[8][256];
    __shared__ float la[8][128];
    __shared__ float lu[8][8];
    const int tid = threadIdx.x;
    const int row0 = blockIdx.x * 8;

    ((float4*)&ly[0][0])[tid] = ((const float4*)(y + (size_t)row0 * 128))[tid];
    if (tid < 16)
        ((float4*)&lu[0][0])[tid] = ((const float4*)(u + (size_t)row0 * 8))[tid];
    __syncthreads();

    {
        float acc[8] = {0,0,0,0,0,0,0,0};
        for (int i = 0; i < 128; i += 4) {
            float w0 = w1[(i+0)*256 + tid];
            float w1v = w1[(i+1)*256 + tid];
            float w2v = w1[(i+2)*256 + tid];
            float w3 = w1[(i+3)*256 + tid];
            #pragma unroll
            for (int r = 0; r < 8; ++r) {
                float4 yv = *(const float4*)&ly[r][i];
                acc[r] += yv.x*w0 + yv.y*w1v + yv.z*w2v + yv.w*w3;
            }
        }
        float bias = b1[tid];
        #pragma unroll
        for (int r = 0; r < 8; ++r) lh[r][tid] = fast_tanh(acc[r] + bias);
    }
    __syncthreads();

    {
        const int d = tid & 127, rh = tid >> 7;
        float acc[4] = {0,0,0,0};
        for (int i = 0; i < 256; i += 4) {
            float w0 = w2[(i+0)*128 + d];
            float w1v = w2[(i+1)*128 + d];
            float w2v = w2[(i+2)*128 + d];
            float w3 = w2[(i+3)*128 + d];
            #pragma unroll
            for (int q = 0; q < 4; ++q) {
                float4 hv = *(const float4*)&lh[rh*4+q][i];
                acc[q] += hv.x*w0 + hv.y*w1v + hv.z*w2v + hv.w*w3;
            }
        }
        float bias = b2[d];
        #pragma unroll
        for (int q = 0; q < 4; ++q) la[rh*4+q][d] = acc[q] + bias;
    }
    __syncthreads();

    {
        const int j = tid & 127, rh = tid >> 7;
        float acc[4] = {0,0,0,0};
        for (int i = 0; i < 128; i += 4) {
            float w0 = wa[(i+0)*128 + j];
            float w1v = wa[(i+1)*128 + j];
            float w2v = wa[(i+2)*128 + j];
            float w3 = wa[(i+3)*128 + j];
            #pragma unroll
            for (int q = 0; q < 4; ++q) {
                float4 av = *(const float4*)&la[rh*4+q][i];
                acc[q] += av.x*w0 + av.y*w1v + av.z*w2v + av.w*w3;
            }
        }
        float bias = bb[j];
        #pragma unroll
        for (int q = 0; q < 4; ++q) {
            int rn = row0 + rh*4 + q;
            int n = rn >> 10, t = rn & 1023;
            apre[((size_t)t*NB + n)*128 + j] = acc[q] + bias;
        }
    }

    {
        float wu[8];
        #pragma unroll
        for (int c = 0; c < 8; ++c) wu[c] = dynw1[(64 + c)*256 + tid];
        float bias = dynb1[tid];
        #pragma unroll
        for (int r = 0; r < 8; ++r) {
            float acc = bias;
            #pragma unroll
            for (int c = 0; c < 8; ++c) acc += lu[r][c] * wu[c];
            int rn = row0 + r;
            int n = rn >> 10, t = rn & 1023;
            preU[((size_t)t*NB + n)*256 + tid] = acc;
        }
    }
}

// -------------------------------------------------------------------------
// K2: backward RNN scan — 256 threads (4 waves, 1/SIMD), 1 batch/block.
// thread (j = tid>>1, p = tid&1): 64-MAC partial (32 dot2) of column j over
// h_f16[p*64..+63]; ONE DPP (xor1) pair-reduce. ONE barrier/step.
// State reads: 2 distinct broadcast addresses/instr -> conflict-free.
// -------------------------------------------------------------------------
__global__ __launch_bounds__(256, 1) void k_bwscan(
    const float* __restrict__ apre, const float* __restrict__ wh,
    float* __restrict__ hcell)
{
    const int n = blockIdx.x;
    const int tid = threadIdx.x;
    const int j = tid >> 1, p = tid & 1;
    __shared__ _Float16 h[2][128];

    h2 w[32];   // Wh[p*64+2k..+1][j], fully-unrolled constant indexing
    {
        const float* s = wh + (size_t)(p * 64) * 128 + j;
        #pragma unroll
        for (int k = 0; k < 32; ++k)
            w[k] = h2{(_Float16)s[(2*k)*128], (_Float16)s[(2*k+1)*128]};
    }

    if (tid < 128) h[0][tid] = (_Float16)0.f;
    __syncthreads();

    float apA = apre[((size_t)1023*NB + n)*128 + j];
    float apB = apre[((size_t)1022*NB + n)*128 + j];

#define BWSTEP(cur, nxt, apv, tt) do { \
        const _Float16* hb = &h[cur][p*64]; \
        float4 mr[8]; \
        _Pragma("unroll") \
        for (int k = 0; k < 8; ++k) mr[k] = ((const float4*)hb)[k]; \
        float c0 = 0.f, c1 = 0.f, c2 = 0.f, c3 = 0.f; \
        _Pragma("unroll") \
        for (int k = 0; k < 8; ++k) { \
            c0 = dot2(f2h2(mr[k].x), w[4*k+0], c0); \
            c1 = dot2(f2h2(mr[k].y), w[4*k+1], c1); \
            c2 = dot2(f2h2(mr[k].z), w[4*k+2], c2); \
            c3 = dot2(f2h2(mr[k].w), w[4*k+3], c3); \
        } \
        float acc = (c0+c1) + (c2+c3); \
        DPP_ADD(acc, 0xB1); \
        float hc = fast_tanh(acc + apv); \
        if (p == 0) h[nxt][j] = (_Float16)hc; \
        else        hcell[((size_t)(tt)*NB + n)*128 + j] = hc; \
        bar_sync(); } while (0)

    for (int t = 1023; t > 0; t -= 2) {
        float apN0 = 0.f, apN1 = 0.f;
        if (t - 2 >= 0) apN0 = apre[((size_t)(t-2)*NB + n)*128 + j];
        BWSTEP(0, 1, apA, t);
        if (t - 3 >= 0) apN1 = apre[((size_t)(t-3)*NB + n)*128 + j];
        BWSTEP(1, 0, apB, t - 1);
        apA = apN0; apB = apN1;
    }
#undef BWSTEP
}

// -------------------------------------------------------------------------
// K3: b = hcell @ wo + bo; alpha PACKED as float2 pairs (unchanged)
// -------------------------------------------------------------------------
__global__ __launch_bounds__(256) void k_alpha(
    const float* __restrict__ hcell, const float* __restrict__ wo,
    const float* __restrict__ bo, float* __restrict__ alpha)
{
    __shared__ float lhc[8][128];
    const int tid = threadIdx.x;
    const size_t base = (size_t)blockIdx.x * 8 * 128;
    ((float4*)&lhc[0][0])[tid] = ((const float4*)(hcell + base))[tid];
    __syncthreads();

    const int j = tid & 127, rh = tid >> 7;
    float acc[4] = {0,0,0,0};
    for (int i = 0; i < 128; i += 4) {
        float w0 = wo[(i+0)*128 + j];
        float w1v = wo[(i+1)*128 + j];
        float w2v = wo[(i+2)*128 + j];
        float w3 = wo[(i+3)*128 + j];
        #pragma unroll
        for (int q = 0; q < 4; ++q) {
            float4 hv = *(const float4*)&lhc[rh*4+q][i];
            acc[q] += hv.x*w0 + hv.y*w1v + hv.z*w2v + hv.w*w3;
        }
    }
    float bias = bo[j];
    const int dpos = (j & 63) * 2 + (j >> 6);   // interleaved pair layout
    #pragma unroll
    for (int q = 0; q < 4; ++q) {
        float b = acc[q] + bias;
        float val = (j < 64) ? b : -softplus_f(b);
        alpha[base + (size_t)(rh*4+q)*128 + dpos] = val;
    }
}

// -------------------------------------------------------------------------
// K4: forward posterior scan. 256 threads (4 waves, 1/SIMD), 1 batch/block.
// L1: hh = tid, ONE hidden/thread: 64-deep (32 dot2), NO DPP, no replication.
// L2: (d2 = tid>>2, qq = tid&3): 64-deep slice (32 dot2) + 2 DPP (quad);
//     epilogue x4 replication; each quad lane stores one of {m_s,v_s,m_p,v_p}.
// 2 barriers/step; alpha packed float2; named/unrolled regs (rule #20).
// -------------------------------------------------------------------------
#define LHF(x) ((x) + (((x) >> 4) << 3))   // pad 8 f16 per 16-elem chunk

__global__ __launch_bounds__(256, 1) void k_fwscan(
    const float* __restrict__ alpha, const float* __restrict__ preU,
    const float* __restrict__ dynw1, const float* __restrict__ dynw2,
    const float* __restrict__ dynb2, const float* __restrict__ qraw,
    const float* __restrict__ m0, const float* __restrict__ v0,
    float* __restrict__ out)
{
    const int n = blockIdx.x;
    const int tid = threadIdx.x;
    const int hh = tid;
    const int d2 = tid >> 2, qq = tid & 3;
    __shared__ _Float16 lm[2][64];
    __shared__ _Float16 lhid[384];

    h2 u[32];   // W1[2k..2k+1][hh], k=0..31 (full 64-deep m column)
    {
        const float* s = dynw1 + hh;
        #pragma unroll
        for (int k = 0; k < 32; ++k)
            u[k] = h2{(_Float16)s[(2*k)*256], (_Float16)s[(2*k+1)*256]};
    }
    h2 v[32];   // W2[qq*64+2k..+1][d2], k=0..31
    {
        const float* s = dynw2 + (size_t)(qq * 64) * 64 + d2;
        #pragma unroll
        for (int k = 0; k < 32; ++k)
            v[k] = h2{(_Float16)s[(2*k)*64], (_Float16)s[(2*k+1)*64]};
    }

    const float Qv  = softplus_f(qraw[d2]);
    const float b2v = dynb2[d2];
    float vreg = v0[d2];
    if (tid < 64) lm[0][tid] = (_Float16)m0[tid];

    // prefetch ring, distance 2
    float hp0 = preU[(size_t)n * 256 + hh];
    float hp1 = preU[((size_t)NB + n)*256 + hh];
    float2 av0 = *(const float2*)&alpha[(size_t)n * 128 + d2*2];
    float2 av1 = *(const float2*)&alpha[((size_t)NB + n)*128 + d2*2];
    __syncthreads();

    int cur = 0;
    for (int t = 0; t < T_LEN; ++t) {
        float hpN = 0.f;
        float2 avN = make_float2(0.f, 0.f);
        if (t + 2 < T_LEN) {
            hpN = preU[((size_t)(t+2)*NB + n)*256 + hh];
            avN = *(const float2*)&alpha[((size_t)(t+2)*NB + n)*128 + d2*2];
        }

        // L1: full 64-deep dot per thread (broadcast m reads), no reduce
        {
            const _Float16* mb = &lm[cur][0];
            float4 mr[8];
            #pragma unroll
            for (int k = 0; k < 8; ++k) mr[k] = ((const float4*)mb)[k];
            float c0 = 0.f, c1 = 0.f, c2 = 0.f, c3 = 0.f;
            #pragma unroll
            for (int k = 0; k < 8; ++k) {
                c0 = dot2(f2h2(mr[k].x), u[4*k+0], c0);
                c1 = dot2(f2h2(mr[k].y), u[4*k+1], c1);
                c2 = dot2(f2h2(mr[k].z), u[4*k+2], c2);
                c3 = dot2(f2h2(mr[k].w), u[4*k+3], c3);
            }
            float acc = (c0+c1) + (c2+c3);
            lhid[LHF(hh)] = (_Float16)fast_tanh(hp0 + acc);
        }
        bar_sync();

        // L2: 64-deep slice over hid (4 chunk-correct pointers) + quad DPP
        {
            float4 hr[8];
            #pragma unroll
            for (int c = 0; c < 4; ++c) {
                const _Float16* hb = &lhid[LHF(qq*64 + 16*c)];
                hr[2*c+0] = ((const float4*)hb)[0];
                hr[2*c+1] = ((const float4*)hb)[1];
            }
            float c0 = 0.f, c1 = 0.f, c2 = 0.f, c3 = 0.f;
            #pragma unroll
            for (int k = 0; k < 8; ++k) {
                c0 = dot2(f2h2(hr[k].x), v[4*k+0], c0);
                c1 = dot2(f2h2(hr[k].y), v[4*k+1], c1);
                c2 = dot2(f2h2(hr[k].z), v[4*k+2], c2);
                c3 = dot2(f2h2(hr[k].w), v[4*k+3], c3);
            }
            float acc = (c0+c1) + (c2+c3);
            DPP_ADD(acc, 0xB1);
            DPP_ADD(acc, 0x4E);

            float m_p = acc + b2v;
            float v_p = vreg + Qv;
            float rvp = __builtin_amdgcn_rcpf(v_p);
            float e1 = m_p * rvp + av0.x;
            float e2 = av0.y - 0.5f * rvp;
            float v_s = -0.5f * __builtin_amdgcn_rcpf(e2);
            float m_s = v_s * e1;
            vreg = v_s;
            if (qq == 0) lm[cur ^ 1][d2] = (_Float16)m_s;

            size_t ob = ((size_t)n * T_LEN + t) * 256;
            float val = (qq == 0) ? m_s : (qq == 1) ? v_s : (qq == 2) ? m_p : v_p;
            out[ob + (size_t)qq*64 + d2] = val;
        }
        bar_sync();
        cur ^= 1;
        hp0 = hp1; hp1 = hpN;
        av0 = av1; av1 = avN;
    }
}

// -------------------------------------------------------------------------
extern "C" void kernel_launch(void* const* d_in, const int* in_sizes, int n_in,
                              void* d_out, int out_size, void* d_ws, size_t ws_size,
                              hipStream_t stream) {
    const float* y      = (const float*)d_in[1];
    const float* u      = (const float*)d_in[2];
    const float* enc_w1 = (const float*)d_in[3];
    const float* enc_b1 = (const float*)d_in[4];
    const float* enc_w2 = (const float*)d_in[5];
    const float* enc_b2 = (const float*)d_in[6];
    const float* bw_wa  = (const float*)d_in[7];
    const float* bw_wh  = (const float*)d_in[8];
    const float* bw_b   = (const float*)d_in[9];
    const float* bw_wo  = (const float*)d_in[10];
    const float* bw_bo  = (const float*)d_in[11];
    const float* dyn_w1 = (const float*)d_in[12];
    const float* dyn_b1 = (const float*)d_in[13];
    const float* dyn_w2 = (const float*)d_in[14];
    const float* dyn_b2 = (const float*)d_in[15];
    const float* q_raw  = (const float*)d_in[16];
    const float* m0     = (const float*)d_in[17];
    const float* v0     = (const float*)d_in[18];
    float* out = (float*)d_out;

    float* ws = (float*)d_ws;
    float* apre  = ws;                  // [T*NB][128]
    float* hcell = ws + 4194304;        // [T*NB][128]
    float* alpha = ws;                  // aliases apre (packed float2 pairs)
    float* preU  = ws + 2 * 4194304;    // [T*NB][256]

    k_encoder<<<4096, 256, 0, stream>>>(y, u, enc_w1, enc_b1, enc_w2, enc_b2,
                                        bw_wa, bw_b, dyn_w1, dyn_b1, apre, preU);
    k_bwscan<<<NB, 256, 0, stream>>>(apre, bw_wh, hcell);
    k_alpha<<<4096, 256, 0, stream>>>(hcell, bw_wo, bw_bo, alpha);
    k_fwscan<<<NB, 256, 0, stream>>>(alpha, preU, dyn_w1, dyn_w2, dyn_b2,
                                     q_raw, m0, v0, out);
}

// Round 18
// 1109.375 us; speedup vs baseline: 17.0633x; 1.0052x over previous
//
#include <hip/hip_runtime.h>
#include <math.h>

// XFADS: N=32, T=1024, D_OBS=128, D_Z=64, D_U=8, H_ENC=256, H_BW=128, H_DYN=256, D_A=128
#define T_LEN 1024
#define NB 32

typedef _Float16 h2 __attribute__((ext_vector_type(2)));

__device__ __forceinline__ h2 f2h2(float f) { return __builtin_bit_cast(h2, f); }

__device__ __forceinline__ float dot2(h2 a, h2 b, float c) {
#if __has_builtin(__builtin_amdgcn_fdot2)
    return __builtin_amdgcn_fdot2(a, b, c, false);
#else
    return fmaf((float)a[0], (float)b[0], fmaf((float)a[1], (float)b[1], c));
#endif
}

// cross-lane add via DPP (VALU pipe): 0xB1 = quad xor1 ; 0x4E = quad xor2 ;
// 0x141 = ROW_HALF_MIRROR (xor7 within 8).
#define DPP_ADD(v, ctrl) do { \
    int _xi = __builtin_bit_cast(int, v); \
    int _yi = __builtin_amdgcn_update_dpp(_xi, _xi, (ctrl), 0xF, 0xF, true); \
    v += __builtin_bit_cast(float, _yi); } while (0)

__device__ __forceinline__ float softplus_f(float x) {
    return fmaxf(x, 0.f) + log1pf(expf(-fabsf(x)));
}

__device__ __forceinline__ float fast_tanh(float x) {
    float e = __builtin_amdgcn_exp2f(x * 2.88539008177792681472f);
    float r = __builtin_amdgcn_rcpf(1.f + e);
    return 1.f - 2.f * r;
}

// raw barrier: drain LDS ops only; global prefetches stay in flight
__device__ __forceinline__ void bar_sync() {
    asm volatile("s_waitcnt lgkmcnt(0)" ::: "memory");
    __builtin_amdgcn_s_barrier();
    asm volatile("" ::: "memory");
}

// -------------------------------------------------------------------------
// K1: encoder (unchanged)
// -------------------------------------------------------------------------
__global__ __launch_bounds__(256) void k_encoder(
    const float* __restrict__ y, const float* __restrict__ u,
    const float* __restrict__ w1, const float* __restrict__ b1,
    const float* __restrict__ w2, const float* __restrict__ b2,
    const float* __restrict__ wa, const float* __restrict__ bb,
    const float* __restrict__ dynw1, const float* __restrict__ dynb1,
    float* __restrict__ apre, float* __restrict__ preU)
{
    __shared__ float ly[8][128];
    __shared__ float lh[8][256];
    __shared__ float la[8][128];
    __shared__ float lu[8][8];
    const int tid = threadIdx.x;
    const int row0 = blockIdx.x * 8;

    ((float4*)&ly[0][0])[tid] = ((const float4*)(y + (size_t)row0 * 128))[tid];
    if (tid < 16)
        ((float4*)&lu[0][0])[tid] = ((const float4*)(u + (size_t)row0 * 8))[tid];
    __syncthreads();

    {
        float acc[8] = {0,0,0,0,0,0,0,0};
        for (int i = 0; i < 128; i += 4) {
            float w0 = w1[(i+0)*256 + tid];
            float w1v = w1[(i+1)*256 + tid];
            float w2v = w1[(i+2)*256 + tid];
            float w3 = w1[(i+3)*256 + tid];
            #pragma unroll
            for (int r = 0; r < 8; ++r) {
                float4 yv = *(const float4*)&ly[r][i];
                acc[r] += yv.x*w0 + yv.y*w1v + yv.z*w2v + yv.w*w3;
            }
        }
        float bias = b1[tid];
        #pragma unroll
        for (int r = 0; r < 8; ++r) lh[r][tid] = fast_tanh(acc[r] + bias);
    }
    __syncthreads();

    {
        const int d = tid & 127, rh = tid >> 7;
        float acc[4] = {0,0,0,0};
        for (int i = 0; i < 256; i += 4) {
            float w0 = w2[(i+0)*128 + d];
            float w1v = w2[(i+1)*128 + d];
            float w2v = w2[(i+2)*128 + d];
            float w3 = w2[(i+3)*128 + d];
            #pragma unroll
            for (int q = 0; q < 4; ++q) {
                float4 hv = *(const float4*)&lh[rh*4+q][i];
                acc[q] += hv.x*w0 + hv.y*w1v + hv.z*w2v + hv.w*w3;
            }
        }
        float bias = b2[d];
        #pragma unroll
        for (int q = 0; q < 4; ++q) la[rh*4+q][d] = acc[q] + bias;
    }
    __syncthreads();

    {
        const int j = tid & 127, rh = tid >> 7;
        float acc[4] = {0,0,0,0};
        for (int i = 0; i < 128; i += 4) {
            float w0 = wa[(i+0)*128 + j];
            float w1v = wa[(i+1)*128 + j];
            float w2v = wa[(i+2)*128 + j];
            float w3 = wa[(i+3)*128 + j];
            #pragma unroll
            for (int q = 0; q < 4; ++q) {
                float4 av = *(const float4*)&la[rh*4+q][i];
                acc[q] += av.x*w0 + av.y*w1v + av.z*w2v + av.w*w3;
            }
        }
        float bias = bb[j];
        #pragma unroll
        for (int q = 0; q < 4; ++q) {
            int rn = row0 + rh*4 + q;
            int n = rn >> 10, t = rn & 1023;
            apre[((size_t)t*NB + n)*128 + j] = acc[q] + bias;
        }
    }

    {
        float wu[8];
        #pragma unroll
        for (int c = 0; c < 8; ++c) wu[c] = dynw1[(64 + c)*256 + tid];
        float bias = dynb1[tid];
        #pragma unroll
        for (int r = 0; r < 8; ++r) {
            float acc = bias;
            #pragma unroll
            for (int c = 0; c < 8; ++c) acc += lu[r][c] * wu[c];
            int rn = row0 + r;
            int n = rn >> 10, t = rn & 1023;
            preU[((size_t)t*NB + n)*256 + tid] = acc;
        }
    }
}

// -------------------------------------------------------------------------
// K2: backward RNN scan — r17's measured-best 256-thread form.
// thread (j = tid>>1, p = tid&1): 64-MAC partial (32 dot2) of column j over
// h_f16[p*64..+63]; ONE DPP (xor1) pair-reduce. ONE barrier/step.
// -------------------------------------------------------------------------
__global__ __launch_bounds__(256, 1) void k_bwscan(
    const float* __restrict__ apre, const float* __restrict__ wh,
    float* __restrict__ hcell)
{
    const int n = blockIdx.x;
    const int tid = threadIdx.x;
    const int j = tid >> 1, p = tid & 1;
    __shared__ _Float16 h[2][128];

    h2 w[32];   // Wh[p*64+2k..+1][j], fully-unrolled constant indexing
    {
        const float* s = wh + (size_t)(p * 64) * 128 + j;
        #pragma unroll
        for (int k = 0; k < 32; ++k)
            w[k] = h2{(_Float16)s[(2*k)*128], (_Float16)s[(2*k+1)*128]};
    }

    if (tid < 128) h[0][tid] = (_Float16)0.f;
    __syncthreads();

    float apA = apre[((size_t)1023*NB + n)*128 + j];
    float apB = apre[((size_t)1022*NB + n)*128 + j];

#define BWSTEP(cur, nxt, apv, tt) do { \
        const _Float16* hb = &h[cur][p*64]; \
        float4 mr[8]; \
        _Pragma("unroll") \
        for (int k = 0; k < 8; ++k) mr[k] = ((const float4*)hb)[k]; \
        float c0 = 0.f, c1 = 0.f, c2 = 0.f, c3 = 0.f; \
        _Pragma("unroll") \
        for (int k = 0; k < 8; ++k) { \
            c0 = dot2(f2h2(mr[k].x), w[4*k+0], c0); \
            c1 = dot2(f2h2(mr[k].y), w[4*k+1], c1); \
            c2 = dot2(f2h2(mr[k].z), w[4*k+2], c2); \
            c3 = dot2(f2h2(mr[k].w), w[4*k+3], c3); \
        } \
        float acc = (c0+c1) + (c2+c3); \
        DPP_ADD(acc, 0xB1); \
        float hc = fast_tanh(acc + apv); \
        if (p == 0) h[nxt][j] = (_Float16)hc; \
        else        hcell[((size_t)(tt)*NB + n)*128 + j] = hc; \
        bar_sync(); } while (0)

    for (int t = 1023; t > 0; t -= 2) {
        float apN0 = 0.f, apN1 = 0.f;
        if (t - 2 >= 0) apN0 = apre[((size_t)(t-2)*NB + n)*128 + j];
        BWSTEP(0, 1, apA, t);
        if (t - 3 >= 0) apN1 = apre[((size_t)(t-3)*NB + n)*128 + j];
        BWSTEP(1, 0, apB, t - 1);
        apA = apN0; apB = apN1;
    }
#undef BWSTEP
}

// -------------------------------------------------------------------------
// K3: b = hcell @ wo + bo; alpha PACKED as float2 pairs (unchanged)
// -------------------------------------------------------------------------
__global__ __launch_bounds__(256) void k_alpha(
    const float* __restrict__ hcell, const float* __restrict__ wo,
    const float* __restrict__ bo, float* __restrict__ alpha)
{
    __shared__ float lhc[8][128];
    const int tid = threadIdx.x;
    const size_t base = (size_t)blockIdx.x * 8 * 128;
    ((float4*)&lhc[0][0])[tid] = ((const float4*)(hcell + base))[tid];
    __syncthreads();

    const int j = tid & 127, rh = tid >> 7;
    float acc[4] = {0,0,0,0};
    for (int i = 0; i < 128; i += 4) {
        float w0 = wo[(i+0)*128 + j];
        float w1v = wo[(i+1)*128 + j];
        float w2v = wo[(i+2)*128 + j];
        float w3 = wo[(i+3)*128 + j];
        #pragma unroll
        for (int q = 0; q < 4; ++q) {
            float4 hv = *(const float4*)&lhc[rh*4+q][i];
            acc[q] += hv.x*w0 + hv.y*w1v + hv.z*w2v + hv.w*w3;
        }
    }
    float bias = bo[j];
    const int dpos = (j & 63) * 2 + (j >> 6);   // interleaved pair layout
    #pragma unroll
    for (int q = 0; q < 4; ++q) {
        float b = acc[q] + bias;
        float val = (j < 64) ? b : -softplus_f(b);
        alpha[base + (size_t)(rh*4+q)*128 + dpos] = val;
    }
}

// -------------------------------------------------------------------------
// K4: forward posterior scan — r16's measured-best 512-thread form.
// L1: (hh = tid>>1, pp = tid&1): 32-deep slice (16 dot2) + ONE DPP (xor1);
//     pp==0 writes lhid (padded per 16, chunk-correct pointers).
// L2: all 8 waves: (d2 = tid>>3, qq = tid&7): 32-deep slice (16 dot2) +
//     3 DPP (xor1, xor2, half-mirror); epilogue x8 replication.
// 2 barriers/step; alpha as packed float2; named ring registers.
// -------------------------------------------------------------------------
#define LHF(x) ((x) + (((x) >> 4) << 3))   // pad 8 f16 per 16-elem chunk

__global__ __launch_bounds__(512, 1) void k_fwscan(
    const float* __restrict__ alpha, const float* __restrict__ preU,
    const float* __restrict__ dynw1, const float* __restrict__ dynw2,
    const float* __restrict__ dynb2, const float* __restrict__ qraw,
    const float* __restrict__ m0, const float* __restrict__ v0,
    float* __restrict__ out)
{
    const int n = blockIdx.x;
    const int tid = threadIdx.x;
    const int hh = tid >> 1, pp = tid & 1;
    const int d2 = tid >> 3, qq = tid & 7;
    __shared__ _Float16 lm[2][64];
    __shared__ _Float16 lhid[384];

    // W1[pp*32+2k..+1][hh], k=0..15
    h2 u0, u1, u2, u3, u4, u5, u6, u7, u8, u9, ua, ub, uc, ud, ue, uf;
    {
        const float* s = dynw1 + (size_t)(pp * 32) * 256 + hh;
        u0 = h2{(_Float16)s[0*256],  (_Float16)s[1*256]};
        u1 = h2{(_Float16)s[2*256],  (_Float16)s[3*256]};
        u2 = h2{(_Float16)s[4*256],  (_Float16)s[5*256]};
        u3 = h2{(_Float16)s[6*256],  (_Float16)s[7*256]};
        u4 = h2{(_Float16)s[8*256],  (_Float16)s[9*256]};
        u5 = h2{(_Float16)s[10*256], (_Float16)s[11*256]};
        u6 = h2{(_Float16)s[12*256], (_Float16)s[13*256]};
        u7 = h2{(_Float16)s[14*256], (_Float16)s[15*256]};
        u8 = h2{(_Float16)s[16*256], (_Float16)s[17*256]};
        u9 = h2{(_Float16)s[18*256], (_Float16)s[19*256]};
        ua = h2{(_Float16)s[20*256], (_Float16)s[21*256]};
        ub = h2{(_Float16)s[22*256], (_Float16)s[23*256]};
        uc = h2{(_Float16)s[24*256], (_Float16)s[25*256]};
        ud = h2{(_Float16)s[26*256], (_Float16)s[27*256]};
        ue = h2{(_Float16)s[28*256], (_Float16)s[29*256]};
        uf = h2{(_Float16)s[30*256], (_Float16)s[31*256]};
    }
    // W2[qq*32+2k..+1][d2], k=0..15
    h2 v0p, v1p, v2p, v3p, v4p, v5p, v6p, v7p;
    h2 v8p, v9p, vap, vbp, vcp, vdp, vep, vfp;
    {
        const float* s = dynw2 + (size_t)(qq * 32) * 64 + d2;
        v0p = h2{(_Float16)s[0*64],  (_Float16)s[1*64]};
        v1p = h2{(_Float16)s[2*64],  (_Float16)s[3*64]};
        v2p = h2{(_Float16)s[4*64],  (_Float16)s[5*64]};
        v3p = h2{(_Float16)s[6*64],  (_Float16)s[7*64]};
        v4p = h2{(_Float16)s[8*64],  (_Float16)s[9*64]};
        v5p = h2{(_Float16)s[10*64], (_Float16)s[11*64]};
        v6p = h2{(_Float16)s[12*64], (_Float16)s[13*64]};
        v7p = h2{(_Float16)s[14*64], (_Float16)s[15*64]};
        v8p = h2{(_Float16)s[16*64], (_Float16)s[17*64]};
        v9p = h2{(_Float16)s[18*64], (_Float16)s[19*64]};
        vap = h2{(_Float16)s[20*64], (_Float16)s[21*64]};
        vbp = h2{(_Float16)s[22*64], (_Float16)s[23*64]};
        vcp = h2{(_Float16)s[24*64], (_Float16)s[25*64]};
        vdp = h2{(_Float16)s[26*64], (_Float16)s[27*64]};
        vep = h2{(_Float16)s[28*64], (_Float16)s[29*64]};
        vfp = h2{(_Float16)s[30*64], (_Float16)s[31*64]};
    }

    const float Qv  = softplus_f(qraw[d2]);
    const float b2v = dynb2[d2];
    float vreg = v0[d2];
    if (tid < 64) lm[0][tid] = (_Float16)m0[tid];

    // prefetch ring, distance 2
    float hp0 = preU[(size_t)n * 256 + hh];
    float hp1 = preU[((size_t)NB + n)*256 + hh];
    float2 av0 = *(const float2*)&alpha[(size_t)n * 128 + d2*2];
    float2 av1 = *(const float2*)&alpha[((size_t)NB + n)*128 + d2*2];
    __syncthreads();

    int cur = 0;
    for (int t = 0; t < T_LEN; ++t) {
        float hpN = 0.f;
        float2 avN = make_float2(0.f, 0.f);
        if (t + 2 < T_LEN) {
            hpN = preU[((size_t)(t+2)*NB + n)*256 + hh];
            avN = *(const float2*)&alpha[((size_t)(t+2)*NB + n)*128 + d2*2];
        }

        // L1: 32-deep partial over m (broadcast reads), ONE DPP pair-reduce
        {
            const _Float16* mb = &lm[cur][pp*32];
            float4 r0 = *(const float4*)mb;
            float4 r1 = *(const float4*)(mb + 8);
            float4 r2 = *(const float4*)(mb + 16);
            float4 r3 = *(const float4*)(mb + 24);
            float c0 = dot2(f2h2(r0.x), u0, 0.f);
            float c1 = dot2(f2h2(r0.y), u1, 0.f);
            float c2 = dot2(f2h2(r0.z), u2, 0.f);
            float c3 = dot2(f2h2(r0.w), u3, 0.f);
            c0 = dot2(f2h2(r1.x), u4, c0);
            c1 = dot2(f2h2(r1.y), u5, c1);
            c2 = dot2(f2h2(r1.z), u6, c2);
            c3 = dot2(f2h2(r1.w), u7, c3);
            c0 = dot2(f2h2(r2.x), u8, c0);
            c1 = dot2(f2h2(r2.y), u9, c1);
            c2 = dot2(f2h2(r2.z), ua, c2);
            c3 = dot2(f2h2(r2.w), ub, c3);
            c0 = dot2(f2h2(r3.x), uc, c0);
            c1 = dot2(f2h2(r3.y), ud, c1);
            c2 = dot2(f2h2(r3.z), ue, c2);
            c3 = dot2(f2h2(r3.w), uf, c3);
            float acc = (c0+c1) + (c2+c3);
            DPP_ADD(acc, 0xB1);   // pair (pp=0/1) sum
            if (pp == 0) lhid[LHF(hh)] = (_Float16)fast_tanh(hp0 + acc);
        }
        bar_sync();

        // L2: all waves — 32-deep partial + 8-lane DPP allreduce + epilogue
        {
            const _Float16* hbA = &lhid[LHF(qq*32)];        // elems 0..15
            const _Float16* hbB = &lhid[LHF(qq*32 + 16)];   // elems 16..31
            float4 r0 = *(const float4*)hbA;
            float4 r1 = *(const float4*)(hbA + 8);
            float4 r2 = *(const float4*)hbB;
            float4 r3 = *(const float4*)(hbB + 8);
            float c0 = dot2(f2h2(r0.x), v0p, 0.f);
            float c1 = dot2(f2h2(r0.y), v1p, 0.f);
            float c2 = dot2(f2h2(r0.z), v2p, 0.f);
            float c3 = dot2(f2h2(r0.w), v3p, 0.f);
            c0 = dot2(f2h2(r1.x), v4p, c0);
            c1 = dot2(f2h2(r1.y), v5p, c1);
            c2 = dot2(f2h2(r1.z), v6p, c2);
            c3 = dot2(f2h2(r1.w), v7p, c3);
            c0 = dot2(f2h2(r2.x), v8p, c0);
            c1 = dot2(f2h2(r2.y), v9p, c1);
            c2 = dot2(f2h2(r2.z), vap, c2);
            c3 = dot2(f2h2(r2.w), vbp, c3);
            c0 = dot2(f2h2(r3.x), vcp, c0);
            c1 = dot2(f2h2(r3.y), vdp, c1);
            c2 = dot2(f2h2(r3.z), vep, c2);
            c3 = dot2(f2h2(r3.w), vfp, c3);
            float acc = (c0+c1) + (c2+c3);
            DPP_ADD(acc, 0xB1);
            DPP_ADD(acc, 0x4E);
            DPP_ADD(acc, 0x141);

            float m_p = acc + b2v;
            float v_p = vreg + Qv;
            float rvp = __builtin_amdgcn_rcpf(v_p);
            float e1 = m_p * rvp + av0.x;
            float e2 = av0.y - 0.5f * rvp;
            float v_s = -0.5f * __builtin_amdgcn_rcpf(e2);
            float m_s = v_s * e1;
            vreg = v_s;
            if (qq == 0) lm[cur ^ 1][d2] = (_Float16)m_s;

            if (qq < 4) {
                size_t ob = ((size_t)n * T_LEN + t) * 256;
                float val = (qq == 0) ? m_s : (qq == 1) ? v_s : (qq == 2) ? m_p : v_p;
                out[ob + (size_t)qq*64 + d2] = val;
            }
        }
        bar_sync();
        cur ^= 1;
        hp0 = hp1; hp1 = hpN;
        av0 = av1; av1 = avN;
    }
}

// -------------------------------------------------------------------------
extern "C" void kernel_launch(void* const* d_in, const int* in_sizes, int n_in,
                              void* d_out, int out_size, void* d_ws, size_t ws_size,
                              hipStream_t stream) {
    const float* y      = (const float*)d_in[1];
    const float* u      = (const float*)d_in[2];
    const float* enc_w1 = (const float*)d_in[3];
    const float* enc_b1 = (const float*)d_in[4];
    const float* enc_w2 = (const float*)d_in[5];
    const float* enc_b2 = (const float*)d_in[6];
    const float* bw_wa  = (const float*)d_in[7];
    const float* bw_wh  = (const float*)d_in[8];
    const float* bw_b   = (const float*)d_in[9];
    const float* bw_wo  = (const float*)d_in[10];
    const float* bw_bo  = (const float*)d_in[11];
    const float* dyn_w1 = (const float*)d_in[12];
    const float* dyn_b1 = (const float*)d_in[13];
    const float* dyn_w2 = (const float*)d_in[14];
    const float* dyn_b2 = (const float*)d_in[15];
    const float* q_raw  = (const float*)d_in[16];
    const float* m0     = (const float*)d_in[17];
    const float* v0     = (const float*)d_in[18];
    float* out = (float*)d_out;

    float* ws = (float*)d_ws;
    float* apre  = ws;                  // [T*NB][128]
    float* hcell = ws + 4194304;        // [T*NB][128]
    float* alpha = ws;                  // aliases apre (packed float2 pairs)
    float* preU  = ws + 2 * 4194304;    // [T*NB][256]

    k_encoder<<<4096, 256, 0, stream>>>(y, u, enc_w1, enc_b1, enc_w2, enc_b2,
                                        bw_wa, bw_b, dyn_w1, dyn_b1, apre, preU);
    k_bwscan<<<NB, 256, 0, stream>>>(apre, bw_wh, hcell);
    k_alpha<<<4096, 256, 0, stream>>>(hcell, bw_wo, bw_bo, alpha);
    k_fwscan<<<NB, 512, 0, stream>>>(alpha, preU, dyn_w1, dyn_w2, dyn_b2,
                                     q_raw, m0, v0, out);
}